// Round 1
// baseline (5001.005 us; speedup 1.0000x reference)
//
#include <hip/hip_runtime.h>
#include <math.h>

#define BATCH 64
#define HW 56
#define CDIM 96
#define NHEADS 3
#define DHEAD 32
#define WSZ 7
#define NTOK 49
#define SHIFT_ 3
#define NWIN_SIDE 8
#define NWIN_IMG 64
#define NWIN_TOT 4096
#define HID 384
#define NTOKENS (BATCH * HW * HW)   // 200704
#define LN100 4.6051702f

// ---------------- Kernel A1: CPB MLP table (169 entries x 3 heads) ------------
__global__ __launch_bounds__(512) void cpb_table_kernel(
    const float* __restrict__ w1, const float* __restrict__ b1,
    const float* __restrict__ w2, float* __restrict__ tabout) {
  int tid = threadIdx.x;
  if (tid >= 169 * 3) return;
  int e = tid / 3, h = tid - e * 3;
  int i = e / 13, j = e - i * 13;
  // coord value: t = (idx-6)*8/6 ; val = sign(t)*log2(|t|+1)/log2(8)
  float ti = (float)(i - 6) * (8.0f / 6.0f);
  float tj = (float)(j - 6) * (8.0f / 6.0f);
  float sx = (ti > 0.f) ? 1.f : (ti < 0.f ? -1.f : 0.f);
  float sy = (tj > 0.f) ? 1.f : (tj < 0.f ? -1.f : 0.f);
  float tx = sx * log2f(fabsf(ti) + 1.f) * (1.0f / 3.0f);
  float ty = sy * log2f(fabsf(tj) + 1.f) * (1.0f / 3.0f);
  float acc = 0.f;
  for (int jj = 0; jj < 512; ++jj) {
    float hv = tx * w1[jj * 2 + 0] + ty * w1[jj * 2 + 1] + b1[jj];
    float g = 0.5f * hv * (1.f + erff(hv * 0.70710678118654752f));
    acc += g * w2[h * 512 + jj];
  }
  tabout[e * 3 + h] = acc;
}

// ---------------- Kernel A2: 16*sigmoid(rpb) gathered to (3,49,49) -----------
__global__ __launch_bounds__(256) void bias_kernel(
    const float* __restrict__ tabout, float* __restrict__ bias16) {
  int idx = blockIdx.x * 256 + threadIdx.x;
  if (idx >= NHEADS * NTOK * NTOK) return;
  int h = idx / (NTOK * NTOK);
  int rem = idx - h * NTOK * NTOK;
  int i = rem / NTOK, j = rem - i * NTOK;
  int ri = (i / WSZ) - (j / WSZ) + 6;
  int ci = (i % WSZ) - (j % WSZ) + 6;
  int e = ri * 13 + ci;
  float v = tabout[e * 3 + h];
  bias16[idx] = 16.f / (1.f + expf(-v));
}

// ---------------- Kernel B: per-window attention + proj + LN1 + residual -----
__global__ __launch_bounds__(256) void attn_kernel(
    const float* __restrict__ x, const float* __restrict__ mask,
    const float* __restrict__ qkv_w, const float* __restrict__ q_bias,
    const float* __restrict__ v_bias, const float* __restrict__ logit_scale,
    const float* __restrict__ proj_w, const float* __restrict__ proj_b,
    const float* __restrict__ n1g, const float* __restrict__ n1b,
    const float* __restrict__ bias16, float* __restrict__ x1out) {
  __shared__ float xw[NTOK * CDIM];          // window input (kept for residual)
  __shared__ float qb[NTOK * CDIM];          // q (normalized*scale), later AV
  __shared__ float kb[NTOK * CDIM];          // k (normalized), later proj out
  __shared__ float vb[NTOK * CDIM];          // v
  __shared__ float at[NHEADS * NTOK * NTOK]; // attention logits/probs

  int w = blockIdx.x;
  int b = w >> 6, wi = w & 63;
  int wh = wi >> 3, wwc = wi & 7;
  int tid = threadIdx.x;

  // ---- load shifted window ----
  for (int idx = tid; idx < NTOK * CDIM; idx += 256) {
    int t = idx / CDIM, c = idx - t * CDIM;
    int r = t / WSZ, cc = t - r * WSZ;
    int hh = (wh * WSZ + r + SHIFT_) % HW;
    int wcol = (wwc * WSZ + cc + SHIFT_) % HW;
    xw[idx] = x[((size_t)b * (HW * HW) + hh * HW + wcol) * CDIM + c];
  }
  __syncthreads();

  // ---- qkv ----
  for (int idx = tid; idx < NTOK * 3 * CDIM; idx += 256) {
    int t = idx / (3 * CDIM), o = idx - t * (3 * CDIM);
    float acc = (o < CDIM) ? q_bias[o] : (o >= 2 * CDIM ? v_bias[o - 2 * CDIM] : 0.f);
    const float* wrow = qkv_w + o * CDIM;
    const float* xr = xw + t * CDIM;
    for (int c = 0; c < CDIM; ++c) acc += xr[c] * wrow[c];
    if (o < CDIM) qb[t * CDIM + o] = acc;
    else if (o < 2 * CDIM) kb[t * CDIM + (o - CDIM)] = acc;
    else vb[t * CDIM + (o - 2 * CDIM)] = acc;
  }
  __syncthreads();

  // ---- normalize q (fold scale) and k ----
  for (int i = tid; i < 2 * NTOK * NHEADS; i += 256) {
    int isK = (i >= NTOK * NHEADS);
    int r = isK ? i - NTOK * NHEADS : i;
    int t = r / NHEADS, h = r - t * NHEADS;
    float* p = (isK ? kb : qb) + t * CDIM + h * DHEAD;
    float ss = 0.f;
    for (int dd = 0; dd < DHEAD; ++dd) ss += p[dd] * p[dd];
    float inv = 1.f / fmaxf(sqrtf(ss), 1e-12f);
    if (!isK) inv *= expf(fminf(logit_scale[h], LN100));
    for (int dd = 0; dd < DHEAD; ++dd) p[dd] *= inv;
  }
  __syncthreads();

  // ---- logits: qn.kn*scale + 16*sigmoid(rpb) + mask ----
  const float* mrow = mask + (size_t)wi * NTOK * NTOK;
  for (int idx = tid; idx < NHEADS * NTOK * NTOK; idx += 256) {
    int h = idx / (NTOK * NTOK), rem = idx - h * NTOK * NTOK;
    int i = rem / NTOK, j = rem - i * NTOK;
    const float* qp = qb + i * CDIM + h * DHEAD;
    const float* kp = kb + j * CDIM + h * DHEAD;
    float acc = 0.f;
    for (int dd = 0; dd < DHEAD; ++dd) acc += qp[dd] * kp[dd];
    at[idx] = acc + bias16[idx] + mrow[rem];
  }
  __syncthreads();

  // ---- softmax rows ----
  for (int r = tid; r < NHEADS * NTOK; r += 256) {
    float* row = at + r * NTOK;
    float mx = -1e30f;
    for (int j = 0; j < NTOK; ++j) mx = fmaxf(mx, row[j]);
    float s = 0.f;
    for (int j = 0; j < NTOK; ++j) { float e = expf(row[j] - mx); row[j] = e; s += e; }
    float inv = 1.f / s;
    for (int j = 0; j < NTOK; ++j) row[j] *= inv;
  }
  __syncthreads();

  // ---- AV (into qb) ----
  for (int idx = tid; idx < NTOK * CDIM; idx += 256) {
    int t = idx / CDIM, col = idx - t * CDIM;
    int h = col >> 5;
    const float* arow = at + (h * NTOK + t) * NTOK;
    float acc = 0.f;
    for (int j = 0; j < NTOK; ++j) acc += arow[j] * vb[j * CDIM + col];
    qb[idx] = acc;
  }
  __syncthreads();

  // ---- proj (into kb) ----
  for (int idx = tid; idx < NTOK * CDIM; idx += 256) {
    int t = idx / CDIM, c = idx - t * CDIM;
    const float* wrow = proj_w + c * CDIM;
    const float* ar = qb + t * CDIM;
    float acc = proj_b[c];
    for (int k2 = 0; k2 < CDIM; ++k2) acc += ar[k2] * wrow[k2];
    kb[idx] = acc;
  }
  __syncthreads();

  // ---- LN1 + residual, scatter back to unshifted layout ----
  for (int t = tid; t < NTOK; t += 256) {
    const float* pr = kb + t * CDIM;
    float mu = 0.f;
    for (int c = 0; c < CDIM; ++c) mu += pr[c];
    mu *= (1.f / CDIM);
    float var = 0.f;
    for (int c = 0; c < CDIM; ++c) { float d = pr[c] - mu; var += d * d; }
    var *= (1.f / CDIM);
    float rs = rsqrtf(var + 1e-5f);
    int r = t / WSZ, cc = t - r * WSZ;
    int hh = (wh * WSZ + r + SHIFT_) % HW;
    int wcol = (wwc * WSZ + cc + SHIFT_) % HW;
    size_t base = ((size_t)b * (HW * HW) + hh * HW + wcol) * CDIM;
    for (int c = 0; c < CDIM; ++c)
      x1out[base + c] = xw[t * CDIM + c] + (pr[c] - mu) * rs * n1g[c] + n1b[c];
  }
}

// ---------------- Kernel C: per-token MLP + LN2 + residual (in-place) --------
__global__ __launch_bounds__(384) void mlp_kernel(
    const float* __restrict__ fc1_w, const float* __restrict__ fc1_b,
    const float* __restrict__ fc2_w, const float* __restrict__ fc2_b,
    const float* __restrict__ n2g, const float* __restrict__ n2b,
    float* __restrict__ xio) {
  __shared__ float x1s[8 * CDIM];
  __shared__ float hbuf[8 * HID];
  __shared__ float ps[4 * 8 * CDIM];
  __shared__ float ms[8 * CDIM];
  __shared__ float mu_s[8], rs_s[8];
  int tid = threadIdx.x;
  size_t tok0 = (size_t)blockIdx.x * 8;

  for (int idx = tid; idx < 8 * CDIM; idx += 384)
    x1s[idx] = xio[tok0 * CDIM + idx];
  __syncthreads();

  // fc1: one output per thread, 8 tokens in registers
  {
    int o = tid;  // 384 threads == HID
    float bo = fc1_b[o];
    float acc[8];
    #pragma unroll
    for (int t = 0; t < 8; ++t) acc[t] = bo;
    const float* wrow = fc1_w + o * CDIM;
    for (int c = 0; c < CDIM; ++c) {
      float wv = wrow[c];
      #pragma unroll
      for (int t = 0; t < 8; ++t) acc[t] += wv * x1s[t * CDIM + c];
    }
    #pragma unroll
    for (int t = 0; t < 8; ++t) {
      float v = acc[t];
      hbuf[t * HID + o] = 0.5f * v * (1.f + erff(v * 0.70710678118654752f));
    }
  }
  __syncthreads();

  // fc2 partial sums: (c2, quarter of K)
  {
    int c2 = tid % CDIM, qt = tid / CDIM;   // qt in 0..3
    float acc[8];
    #pragma unroll
    for (int t = 0; t < 8; ++t) acc[t] = 0.f;
    const float* wrow = fc2_w + (size_t)c2 * HID + qt * 96;
    for (int oo = 0; oo < 96; ++oo) {
      float wv = wrow[oo];
      int o = qt * 96 + oo;
      #pragma unroll
      for (int t = 0; t < 8; ++t) acc[t] += wv * hbuf[t * HID + o];
    }
    #pragma unroll
    for (int t = 0; t < 8; ++t) ps[(qt * 8 + t) * CDIM + c2] = acc[t];
  }
  __syncthreads();

  // reduce partials + bias
  for (int idx = tid; idx < 8 * CDIM; idx += 384) {
    int t = idx / CDIM, c2 = idx - t * CDIM;
    ms[idx] = fc2_b[c2] + ps[(0 * 8 + t) * CDIM + c2] + ps[(1 * 8 + t) * CDIM + c2]
                        + ps[(2 * 8 + t) * CDIM + c2] + ps[(3 * 8 + t) * CDIM + c2];
  }
  __syncthreads();

  if (tid < 8) {
    int t = tid;
    float mu = 0.f;
    for (int c = 0; c < CDIM; ++c) mu += ms[t * CDIM + c];
    mu *= (1.f / CDIM);
    float var = 0.f;
    for (int c = 0; c < CDIM; ++c) { float d = ms[t * CDIM + c] - mu; var += d * d; }
    var *= (1.f / CDIM);
    mu_s[t] = mu;
    rs_s[t] = rsqrtf(var + 1e-5f);
  }
  __syncthreads();

  for (int idx = tid; idx < 8 * CDIM; idx += 384) {
    int t = idx / CDIM, c = idx - t * CDIM;
    xio[tok0 * CDIM + idx] = x1s[idx] + (ms[idx] - mu_s[t]) * rs_s[t] * n2g[c] + n2b[c];
  }
}

// ---------------- launch ------------------------------------------------------
extern "C" void kernel_launch(void* const* d_in, const int* in_sizes, int n_in,
                              void* d_out, int out_size, void* d_ws, size_t ws_size,
                              hipStream_t stream) {
  const float* x           = (const float*)d_in[0];
  const float* attn_mask   = (const float*)d_in[1];
  const float* qkv_w       = (const float*)d_in[2];
  const float* q_bias      = (const float*)d_in[3];
  const float* v_bias      = (const float*)d_in[4];
  const float* logit_scale = (const float*)d_in[5];
  const float* cpb_w1      = (const float*)d_in[6];
  const float* cpb_b1      = (const float*)d_in[7];
  const float* cpb_w2      = (const float*)d_in[8];
  const float* proj_w      = (const float*)d_in[9];
  const float* proj_b      = (const float*)d_in[10];
  const float* n1g         = (const float*)d_in[11];
  const float* n1b         = (const float*)d_in[12];
  const float* fc1_w       = (const float*)d_in[13];
  const float* fc1_b       = (const float*)d_in[14];
  const float* fc2_w       = (const float*)d_in[15];
  const float* fc2_b       = (const float*)d_in[16];
  const float* n2g         = (const float*)d_in[17];
  const float* n2b         = (const float*)d_in[18];
  float* out = (float*)d_out;

  float* tabout = (float*)d_ws;        // 512 floats (169*3 used)
  float* bias16 = tabout + 512;        // 7203 floats

  cpb_table_kernel<<<1, 512, 0, stream>>>(cpb_w1, cpb_b1, cpb_w2, tabout);
  bias_kernel<<<(NHEADS * NTOK * NTOK + 255) / 256, 256, 0, stream>>>(tabout, bias16);
  attn_kernel<<<NWIN_TOT, 256, 0, stream>>>(x, attn_mask, qkv_w, q_bias, v_bias,
                                            logit_scale, proj_w, proj_b, n1g, n1b,
                                            bias16, out);
  mlp_kernel<<<NTOKENS / 8, 384, 0, stream>>>(fc1_w, fc1_b, fc2_w, fc2_b, n2g, n2b, out);
}

// Round 2
// 1691.605 us; speedup vs baseline: 2.9564x; 2.9564x over previous
//
#include <hip/hip_runtime.h>
#include <math.h>

#define BATCH 64
#define HW 56
#define CDIM 96
#define NHEADS 3
#define WSZ 7
#define NTOK 49
#define SHIFT_ 3
#define NWIN_TOT 4096
#define HID 384
#define NTOKENS (BATCH * HW * HW)   // 200704
#define LN100 4.6051702f

// ---------- bf16 helpers (manual RNE pack, shift-unpack) ----------
__device__ inline unsigned short f2b(float f) {
  unsigned u = __float_as_uint(f);
  unsigned r = (u + 0x7FFFu + ((u >> 16) & 1u)) >> 16;
  return (unsigned short)r;
}
__device__ inline float blo(unsigned u) { return __uint_as_float(u << 16); }
__device__ inline float bhi(unsigned u) { return __uint_as_float(u & 0xFFFF0000u); }
__device__ inline unsigned packb(float a, float b) {
  return (unsigned)f2b(a) | ((unsigned)f2b(b) << 16);
}
__device__ inline void unp8(uint4 w, float* f) {
  f[0] = blo(w.x); f[1] = bhi(w.x); f[2] = blo(w.y); f[3] = bhi(w.y);
  f[4] = blo(w.z); f[5] = bhi(w.z); f[6] = blo(w.w); f[7] = bhi(w.w);
}

// ---------------- P0: weight transpose + bf16 convert ------------------------
__global__ __launch_bounds__(256) void wconv_kernel(
    const float* __restrict__ qkv_w, const float* __restrict__ proj_w,
    const float* __restrict__ fc1_w, const float* __restrict__ fc2_w,
    unsigned short* __restrict__ qkvwT, unsigned short* __restrict__ pwT,
    unsigned short* __restrict__ w1T, unsigned short* __restrict__ w2T) {
  int idx = blockIdx.x * 256 + threadIdx.x;
  if (idx < 27648) { int c = idx / 288, o = idx - c * 288; qkvwT[idx] = f2b(qkv_w[o * 96 + c]); return; }
  idx -= 27648;
  if (idx < 9216) { int k = idx / 96, c = idx - k * 96; pwT[idx] = f2b(proj_w[c * 96 + k]); return; }
  idx -= 9216;
  if (idx < 36864) { int c = idx / 384, o = idx - c * 384; w1T[idx] = f2b(fc1_w[o * 96 + c]); return; }
  idx -= 36864;
  if (idx < 36864) { int k = idx / 96, c = idx - k * 96; w2T[idx] = f2b(fc2_w[c * 384 + k]); return; }
}

// ---------------- P1: CPB MLP table (169 x 3) --------------------------------
__global__ __launch_bounds__(512) void cpb_table_kernel(
    const float* __restrict__ w1, const float* __restrict__ b1,
    const float* __restrict__ w2, float* __restrict__ tabout) {
  int tid = threadIdx.x;
  if (tid >= 169 * 3) return;
  int e = tid / 3, h = tid - e * 3;
  int i = e / 13, j = e - i * 13;
  float ti = (float)(i - 6) * (8.0f / 6.0f);
  float tj = (float)(j - 6) * (8.0f / 6.0f);
  float sx = (ti > 0.f) ? 1.f : (ti < 0.f ? -1.f : 0.f);
  float sy = (tj > 0.f) ? 1.f : (tj < 0.f ? -1.f : 0.f);
  float tx = sx * log2f(fabsf(ti) + 1.f) * (1.0f / 3.0f);
  float ty = sy * log2f(fabsf(tj) + 1.f) * (1.0f / 3.0f);
  float acc = 0.f;
  for (int jj = 0; jj < 512; ++jj) {
    float hv = tx * w1[jj * 2 + 0] + ty * w1[jj * 2 + 1] + b1[jj];
    float g = 0.5f * hv * (1.f + erff(hv * 0.70710678118654752f));
    acc += g * w2[h * 512 + jj];
  }
  tabout[e * 3 + h] = acc;
}

// ---------------- P2: 16*sigmoid(rpb) gathered to (3,49,49) ------------------
__global__ __launch_bounds__(256) void bias_kernel(
    const float* __restrict__ tabout, float* __restrict__ bias16) {
  int idx = blockIdx.x * 256 + threadIdx.x;
  if (idx >= NHEADS * NTOK * NTOK) return;
  int h = idx / (NTOK * NTOK);
  int rem = idx - h * NTOK * NTOK;
  int i = rem / NTOK, j = rem - i * NTOK;
  int ri = (i / WSZ) - (j / WSZ) + 6;
  int ci = (i % WSZ) - (j % WSZ) + 6;
  int e = ri * 13 + ci;
  float v = tabout[e * 3 + h];
  bias16[idx] = 16.f / (1.f + expf(-v));
}

// ---------------- K1: per-window QKV + cosine norm -> bf16 -------------------
// LDS: xsT [96][53] f32 | wsT [96][144] dwords; aliased by outb [49][289] f32.
__global__ __launch_bounds__(256) void qkv_kernel(
    const float* __restrict__ x, const unsigned* __restrict__ qkvwT_u,
    const float* __restrict__ q_bias, const float* __restrict__ v_bias,
    const float* __restrict__ logit_scale,
    unsigned* __restrict__ qws, unsigned* __restrict__ kws,
    unsigned* __restrict__ vws) {
  __shared__ float smem[18912];   // 75648 B -> 2 blocks/CU
  float* xsT = smem;
  unsigned* wsT = (unsigned*)(smem + 5088);
  float* outb = smem;             // alias (used after full sync)
  int win = blockIdx.x, tid = threadIdx.x;
  int b = win >> 6, wi = win & 63, wh = wi >> 3, wcx = wi & 7;

  for (int idx = tid; idx < NTOK * CDIM; idx += 256) {
    int t = idx / 96, c = idx - t * 96;
    int tr = t / 7, tc = t - tr * 7;
    int R = wh * 7 + tr + SHIFT_; if (R >= HW) R -= HW;
    int C = wcx * 7 + tc + SHIFT_; if (C >= HW) C -= HW;
    xsT[c * 53 + t] = x[((size_t)(b * 3136 + R * 56 + C)) * 96 + c];
  }
  for (int idx = tid; idx < 13824; idx += 256) wsT[idx] = qkvwT_u[idx];
  __syncthreads();

  int og = tid % 36, tg = tid / 36;       // 36 o-octets x 7 t-septets = 252 thr
  float acc[7][8] = {};
  if (tg < 7) {
    int t0v = tg * 7;
    for (int c = 0; c < 96; ++c) {
      uint4 wv = *(const uint4*)&wsT[c * 144 + og * 4];
      float w[8]; unp8(wv, w);
      float xv[7];
      #pragma unroll
      for (int tt = 0; tt < 7; ++tt) xv[tt] = xsT[c * 53 + t0v + tt];
      #pragma unroll
      for (int tt = 0; tt < 7; ++tt)
        #pragma unroll
        for (int oo = 0; oo < 8; ++oo) acc[tt][oo] += xv[tt] * w[oo];
    }
  }
  __syncthreads();    // all LDS reads done before aliasing as outb
  if (tg < 7) {
    int o0 = og * 8, t0v = tg * 7;
    #pragma unroll
    for (int oo = 0; oo < 8; ++oo) {
      int o = o0 + oo;
      float bias = (o < 96) ? q_bias[o] : ((o >= 192) ? v_bias[o - 192] : 0.f);
      #pragma unroll
      for (int tt = 0; tt < 7; ++tt) outb[(t0v + tt) * 289 + o] = acc[tt][oo] + bias;
    }
  }
  __syncthreads();

  // normalize q (fold clamped temperature), k; write bf16 [win][h][t][32]
  for (int task = tid; task < 294; task += 256) {
    int t = task / 6, rem = task - t * 6;
    int h = rem >> 1, isK = rem & 1;
    const float* p = outb + t * 289 + isK * 96 + h * 32;
    float vr[32]; float ss = 0.f;
    #pragma unroll
    for (int d = 0; d < 32; ++d) { vr[d] = p[d]; ss += vr[d] * vr[d]; }
    float inv = 1.f / fmaxf(sqrtf(ss), 1e-12f);
    if (!isK) inv *= expf(fminf(logit_scale[h], LN100));
    unsigned* dst = (isK ? kws : qws) + (((size_t)win * 3 + h) * 49 + t) * 16;
    #pragma unroll
    for (int d2 = 0; d2 < 16; ++d2) dst[d2] = packb(vr[2 * d2] * inv, vr[2 * d2 + 1] * inv);
  }
  for (int idx = tid; idx < 2352; idx += 256) {
    int t = idx / 48, cd = idx - t * 48;
    int h = cd >> 4, dh = cd & 15;
    vws[(((size_t)win * 3 + h) * 49 + t) * 16 + dh] =
        packb(outb[t * 289 + 192 + 2 * cd], outb[t * 289 + 193 + 2 * cd]);
  }
}

// ---------------- K2: per-(window,head) attention core -----------------------
// LDS ~20 KB -> 8 blocks/CU (16 waves). Padded strides kill bank conflicts.
__global__ __launch_bounds__(128) void attn_core_kernel(
    const unsigned* __restrict__ qws, const unsigned* __restrict__ kws,
    const unsigned* __restrict__ vws, const float* __restrict__ bias16,
    const float* __restrict__ mask, unsigned* __restrict__ aout) {
  int blk = blockIdx.x;
  int win = blk / 3, h = blk - win * 3;
  int wi = win & 63;
  __shared__ unsigned qs[833], ks[833], vs[784];  // stride 17 dwords for q,k
  __shared__ float P[49 * 53];
  int tid = threadIdx.x;
  size_t base = ((size_t)win * 3 + h) * 784;
  for (int idx = tid; idx < 784; idx += 128) {
    int t = idx >> 4, d2 = idx & 15;
    qs[t * 17 + d2] = qws[base + idx];
    ks[t * 17 + d2] = kws[base + idx];
    vs[idx] = vws[base + idx];
  }
  __syncthreads();

  const float* bsl = bias16 + h * 2401;
  const float* msl = mask + (size_t)wi * 2401;
  for (int task = tid; task < 343; task += 128) {
    int i = task / 7, j0 = (task - i * 7) * 7;
    float acc[7] = {0, 0, 0, 0, 0, 0, 0};
    for (int d2 = 0; d2 < 16; ++d2) {
      unsigned qv = qs[i * 17 + d2];
      float q0 = blo(qv), q1 = bhi(qv);
      #pragma unroll
      for (int jj = 0; jj < 7; ++jj) {
        unsigned kv = ks[(j0 + jj) * 17 + d2];
        acc[jj] += q0 * blo(kv) + q1 * bhi(kv);
      }
    }
    #pragma unroll
    for (int jj = 0; jj < 7; ++jj) {
      int j = j0 + jj;
      P[i * 53 + j] = acc[jj] + bsl[i * 49 + j] + msl[i * 49 + j];
    }
  }
  __syncthreads();

  if (tid < 49) {
    float* row = P + tid * 53;
    float mx = -1e30f;
    for (int j = 0; j < 49; ++j) mx = fmaxf(mx, row[j]);
    float s = 0.f;
    for (int j = 0; j < 49; ++j) { float e = expf(row[j] - mx); row[j] = e; s += e; }
    float inv = 1.f / s;
    for (int j = 0; j < 49; ++j) row[j] *= inv;
  }
  __syncthreads();

  for (int task = tid; task < 196; task += 128) {
    int t = task >> 2, dg = task & 3;
    float acc[8] = {0, 0, 0, 0, 0, 0, 0, 0};
    for (int j = 0; j < 49; ++j) {
      float p = P[t * 53 + j];
      uint4 vv = *(const uint4*)&vs[j * 16 + dg * 4];
      float vf[8]; unp8(vv, vf);
      #pragma unroll
      for (int oo = 0; oo < 8; ++oo) acc[oo] += p * vf[oo];
    }
    uint4 o4;
    o4.x = packb(acc[0], acc[1]); o4.y = packb(acc[2], acc[3]);
    o4.z = packb(acc[4], acc[5]); o4.w = packb(acc[6], acc[7]);
    *(uint4*)&aout[(((size_t)win * 49 + t)) * 48 + h * 16 + dg * 4] = o4;
  }
}

// ---------------- K3: proj + LN1 + residual (scatter to original layout) -----
__global__ __launch_bounds__(256) void proj_ln_kernel(
    const unsigned* __restrict__ aout, const unsigned* __restrict__ pwT_u,
    const float* __restrict__ proj_b, const float* __restrict__ x,
    const float* __restrict__ n1g, const float* __restrict__ n1b,
    float* __restrict__ out) {
  __shared__ unsigned pw[4608];     // [96][48] dwords
  __shared__ unsigned at[32 * 49];  // padded stride 49
  __shared__ float yb[32 * 97];
  __shared__ float mu_s[32], rs_s[32];
  int tid = threadIdx.x;
  int wt0 = blockIdx.x * 32;
  for (int idx = tid; idx < 4608; idx += 256) pw[idx] = pwT_u[idx];
  for (int idx = tid; idx < 1536; idx += 256) {
    int t = idx / 48, k2 = idx - t * 48;
    at[t * 49 + k2] = aout[(size_t)wt0 * 48 + idx];
  }
  __syncthreads();

  int cg = tid % 12, tg = tid / 12;
  if (tg < 16) {
    int t0 = tg * 2, c0 = cg * 8;
    float acc[2][8] = {};
    for (int k2 = 0; k2 < 48; ++k2) {
      unsigned a0 = at[t0 * 49 + k2], a1 = at[(t0 + 1) * 49 + k2];
      uint4 w0 = *(const uint4*)&pw[(2 * k2) * 48 + cg * 4];
      uint4 w1 = *(const uint4*)&pw[(2 * k2) * 48 + 48 + cg * 4];
      float wl[8], wh2[8]; unp8(w0, wl); unp8(w1, wh2);
      float a00 = blo(a0), a01 = bhi(a0), a10 = blo(a1), a11 = bhi(a1);
      #pragma unroll
      for (int oo = 0; oo < 8; ++oo) {
        acc[0][oo] += a00 * wl[oo] + a01 * wh2[oo];
        acc[1][oo] += a10 * wl[oo] + a11 * wh2[oo];
      }
    }
    #pragma unroll
    for (int tt = 0; tt < 2; ++tt)
      #pragma unroll
      for (int oo = 0; oo < 8; ++oo)
        yb[(t0 + tt) * 97 + c0 + oo] = acc[tt][oo] + proj_b[c0 + oo];
  }
  __syncthreads();

  if (tid < 32) {
    const float* row = yb + tid * 97;
    float mu = 0.f;
    for (int c = 0; c < 96; ++c) mu += row[c];
    mu *= (1.f / 96.f);
    float var = 0.f;
    for (int c = 0; c < 96; ++c) { float d = row[c] - mu; var += d * d; }
    var *= (1.f / 96.f);
    mu_s[tid] = mu;
    rs_s[tid] = rsqrtf(var + 1e-5f);
  }
  __syncthreads();

  for (int idx = tid; idx < 3072; idx += 256) {
    int t = idx / 96, c = idx - t * 96;
    int wt = wt0 + t;
    int win = wt / 49, tt2 = wt - win * 49;
    int b = win >> 6, wi = win & 63, wh = wi >> 3, wcx = wi & 7;
    int tr = tt2 / 7, tc = tt2 - tr * 7;
    int R = wh * 7 + tr + SHIFT_; if (R >= HW) R -= HW;
    int C = wcx * 7 + tc + SHIFT_; if (C >= HW) C -= HW;
    size_t orig = ((size_t)(b * 3136 + R * 56 + C)) * 96 + c;
    out[orig] = x[orig] + (yb[t * 97 + c] - mu_s[t]) * rs_s[t] * n1g[c] + n1b[c];
  }
}

// ---------------- K4: MLP + LN2 + residual (in-place, 32 tokens/block) -------
__global__ __launch_bounds__(256) void mlp_kernel2(
    const unsigned* __restrict__ w1T_u, const float* __restrict__ fc1_b,
    const unsigned* __restrict__ w2T_u, const float* __restrict__ fc2_b,
    const float* __restrict__ n2g, const float* __restrict__ n2b,
    float* __restrict__ xio) {
  __shared__ float x1s[32 * 98];
  __shared__ unsigned wc[6144];     // fc1 chunk [96][64] / fc2 chunk [128][48]
  __shared__ unsigned hb[32 * 196]; // hidden, bf16 pairs, padded stride
  __shared__ float yb[32 * 97];
  __shared__ float mu_s[32], rs_s[32];
  int tid = threadIdx.x;
  size_t tok0 = (size_t)blockIdx.x * 32;
  float* xin = xio + tok0 * 96;

  for (int idx = tid; idx < 3072; idx += 256) {
    int t = idx / 96, c = idx - t * 96;
    x1s[t * 98 + c] = xin[idx];
  }
  __syncthreads();

  // ---- fc1 + GELU (3 chunks of 128 outputs) ----
  int og = tid & 15, tg = tid >> 4;   // 16 x 16
  int t0 = tg * 2;
  for (int oc = 0; oc < 3; ++oc) {
    for (int idx = tid; idx < 6144; idx += 256) {
      int c = idx >> 6, od = idx & 63;
      wc[idx] = w1T_u[c * 192 + oc * 64 + od];
    }
    __syncthreads();
    float acc[2][8] = {};
    for (int c2 = 0; c2 < 48; ++c2) {
      int c = c2 * 2;
      float xa0 = x1s[t0 * 98 + c], xa1 = x1s[t0 * 98 + c + 1];
      float xb0 = x1s[(t0 + 1) * 98 + c], xb1 = x1s[(t0 + 1) * 98 + c + 1];
      uint4 w0 = *(const uint4*)&wc[c * 64 + og * 4];
      uint4 w1 = *(const uint4*)&wc[(c + 1) * 64 + og * 4];
      float wl[8], wh2[8]; unp8(w0, wl); unp8(w1, wh2);
      #pragma unroll
      for (int oo = 0; oo < 8; ++oo) {
        acc[0][oo] += xa0 * wl[oo] + xa1 * wh2[oo];
        acc[1][oo] += xb0 * wl[oo] + xb1 * wh2[oo];
      }
    }
    #pragma unroll
    for (int tt = 0; tt < 2; ++tt) {
      #pragma unroll
      for (int op = 0; op < 4; ++op) {
        int o = oc * 128 + og * 8 + 2 * op;
        float v0 = acc[tt][2 * op] + fc1_b[o];
        float v1 = acc[tt][2 * op + 1] + fc1_b[o + 1];
        float g0 = 0.5f * v0 * (1.f + erff(v0 * 0.70710678118654752f));
        float g1 = 0.5f * v1 * (1.f + erff(v1 * 0.70710678118654752f));
        hb[(t0 + tt) * 196 + oc * 64 + og * 4 + op] = packb(g0, g1);
      }
    }
    __syncthreads();
  }

  // ---- fc2 (3 chunks of 128 k), acc persists in regs ----
  int cg = tid % 12, tg2 = tid / 12;
  bool act = (tg2 < 16);
  int t0b = tg2 * 2, c0 = cg * 8;
  float acc2[2][8] = {};
  for (int kc = 0; kc < 3; ++kc) {
    for (int idx = tid; idx < 6144; idx += 256) wc[idx] = w2T_u[kc * 6144 + idx];
    __syncthreads();
    if (act) {
      for (int k2 = 0; k2 < 64; ++k2) {
        unsigned h0 = hb[t0b * 196 + kc * 64 + k2];
        unsigned h1 = hb[(t0b + 1) * 196 + kc * 64 + k2];
        int kl = k2 * 2;
        uint4 w0 = *(const uint4*)&wc[kl * 48 + cg * 4];
        uint4 w1 = *(const uint4*)&wc[(kl + 1) * 48 + cg * 4];
        float wl[8], wh2[8]; unp8(w0, wl); unp8(w1, wh2);
        float h00 = blo(h0), h01 = bhi(h0), h10 = blo(h1), h11 = bhi(h1);
        #pragma unroll
        for (int oo = 0; oo < 8; ++oo) {
          acc2[0][oo] += h00 * wl[oo] + h01 * wh2[oo];
          acc2[1][oo] += h10 * wl[oo] + h11 * wh2[oo];
        }
      }
    }
    __syncthreads();
  }
  if (act) {
    #pragma unroll
    for (int tt = 0; tt < 2; ++tt)
      #pragma unroll
      for (int oo = 0; oo < 8; ++oo)
        yb[(t0b + tt) * 97 + c0 + oo] = acc2[tt][oo] + fc2_b[c0 + oo];
  }
  __syncthreads();

  if (tid < 32) {
    const float* row = yb + tid * 97;
    float mu = 0.f;
    for (int c = 0; c < 96; ++c) mu += row[c];
    mu *= (1.f / 96.f);
    float var = 0.f;
    for (int c = 0; c < 96; ++c) { float d = row[c] - mu; var += d * d; }
    var *= (1.f / 96.f);
    mu_s[tid] = mu;
    rs_s[tid] = rsqrtf(var + 1e-5f);
  }
  __syncthreads();

  for (int idx = tid; idx < 3072; idx += 256) {
    int t = idx / 96, c = idx - t * 96;
    xin[idx] = x1s[t * 98 + c] + (yb[t * 97 + c] - mu_s[t]) * rs_s[t] * n2g[c] + n2b[c];
  }
}

// ---------------- launch ------------------------------------------------------
extern "C" void kernel_launch(void* const* d_in, const int* in_sizes, int n_in,
                              void* d_out, int out_size, void* d_ws, size_t ws_size,
                              hipStream_t stream) {
  const float* x           = (const float*)d_in[0];
  const float* attn_mask   = (const float*)d_in[1];
  const float* qkv_w       = (const float*)d_in[2];
  const float* q_bias      = (const float*)d_in[3];
  const float* v_bias      = (const float*)d_in[4];
  const float* logit_scale = (const float*)d_in[5];
  const float* cpb_w1      = (const float*)d_in[6];
  const float* cpb_b1      = (const float*)d_in[7];
  const float* cpb_w2      = (const float*)d_in[8];
  const float* proj_w      = (const float*)d_in[9];
  const float* proj_b      = (const float*)d_in[10];
  const float* n1g         = (const float*)d_in[11];
  const float* n1b         = (const float*)d_in[12];
  const float* fc1_w       = (const float*)d_in[13];
  const float* fc1_b       = (const float*)d_in[14];
  const float* fc2_w       = (const float*)d_in[15];
  const float* fc2_b       = (const float*)d_in[16];
  const float* n2g         = (const float*)d_in[17];
  const float* n2b         = (const float*)d_in[18];
  float* out = (float*)d_out;

  // ---- workspace layout (~154.4 MB total) ----
  float* bias16 = (float*)d_ws;                              // 7203 f32 (pad 7296)
  float* tab    = bias16 + 7296;                             // 512 f32
  unsigned short* qkvwT = (unsigned short*)(tab + 512);      // 27648 bf16
  unsigned short* pwT   = qkvwT + 27648;                     // 9216
  unsigned short* w1T   = pwT + 9216;                        // 36864
  unsigned short* w2T   = w1T + 36864;                       // 36864
  unsigned* qws  = (unsigned*)(w2T + 36864);                 // 9,633,792 dwords
  unsigned* kws  = qws + 9633792;
  unsigned* vws  = kws + 9633792;
  unsigned* aout = vws + 9633792;

  wconv_kernel<<<432, 256, 0, stream>>>(qkv_w, proj_w, fc1_w, fc2_w,
                                        qkvwT, pwT, w1T, w2T);
  cpb_table_kernel<<<1, 512, 0, stream>>>(cpb_w1, cpb_b1, cpb_w2, tab);
  bias_kernel<<<(NHEADS * NTOK * NTOK + 255) / 256, 256, 0, stream>>>(tab, bias16);
  qkv_kernel<<<NWIN_TOT, 256, 0, stream>>>(x, (const unsigned*)qkvwT, q_bias, v_bias,
                                           logit_scale, qws, kws, vws);
  attn_core_kernel<<<NWIN_TOT * 3, 128, 0, stream>>>(qws, kws, vws, bias16,
                                                     attn_mask, aout);
  proj_ln_kernel<<<NTOKENS / 32, 256, 0, stream>>>(aout, (const unsigned*)pwT,
                                                   proj_b, x, n1g, n1b, out);
  mlp_kernel2<<<NTOKENS / 32, 256, 0, stream>>>((const unsigned*)w1T, fc1_b,
                                                (const unsigned*)w2T, fc2_b,
                                                n2g, n2b, out);
}

// Round 3
// 878.216 us; speedup vs baseline: 5.6945x; 1.9262x over previous
//
#include <hip/hip_runtime.h>
#include <math.h>

#define BATCH 64
#define HW 56
#define CDIM 96
#define NHEADS 3
#define WSZ 7
#define NTOK 49
#define SHIFT_ 3
#define NWIN_TOT 4096
#define HID 384
#define NTOKENS (BATCH * HW * HW)   // 200704
#define LN100 4.6051702f

typedef __attribute__((ext_vector_type(8))) short bf16x8;
typedef __attribute__((ext_vector_type(4))) float f32x4;

__device__ inline f32x4 mfma16(bf16x8 a, bf16x8 b, f32x4 c) {
  return __builtin_amdgcn_mfma_f32_16x16x32_bf16(a, b, c, 0, 0, 0);
}

// ---------- bf16 helpers ----------
__device__ inline unsigned short f2b(float f) {
  unsigned u = __float_as_uint(f);
  unsigned r = (u + 0x7FFFu + ((u >> 16) & 1u)) >> 16;
  return (unsigned short)r;
}
__device__ inline float blo(unsigned u) { return __uint_as_float(u << 16); }
__device__ inline float bhi(unsigned u) { return __uint_as_float(u & 0xFFFF0000u); }
__device__ inline unsigned packb(float a, float b) {
  return (unsigned)f2b(a) | ((unsigned)f2b(b) << 16);
}
__device__ inline void unp8(uint4 w, float* f) {
  f[0] = blo(w.x); f[1] = bhi(w.x); f[2] = blo(w.y); f[3] = bhi(w.y);
  f[4] = blo(w.z); f[5] = bhi(w.z); f[6] = blo(w.w); f[7] = bhi(w.w);
}

// ---------------- P0: weight conversion into MFMA B-frag layouts --------------
// B-frag for 16x16x32: lane l holds B[k0+j][col], k0=(l>>4)*8, col=(l&15), j=0..7.
__global__ __launch_bounds__(256) void wconv2_kernel(
    const float* __restrict__ qkv_w, const float* __restrict__ fc1_w,
    const float* __restrict__ fc2_w, const float* __restrict__ proj_w,
    unsigned* __restrict__ qkvf, unsigned* __restrict__ w1f,
    unsigned* __restrict__ w2f, unsigned short* __restrict__ pwT) {
  int T = blockIdx.x * 256 + threadIdx.x;
  if (T < 3456) {  // qkv: 18 n-tiles x 3 k-steps
    int tk = T >> 6, l = T & 63;
    int n = tk / 3, ks = tk - n * 3;
    int o = n * 16 + (l & 15);
    const float* src = qkv_w + o * 96 + ks * 32 + (l >> 4) * 8;
    uint4 d;
    d.x = packb(src[0], src[1]); d.y = packb(src[2], src[3]);
    d.z = packb(src[4], src[5]); d.w = packb(src[6], src[7]);
    *(uint4*)&qkvf[(size_t)(tk * 64 + l) * 4] = d;
    return;
  }
  T -= 3456;
  if (T < 4608) {  // fc1: 24 n-tiles x 3 k-steps
    int tk = T >> 6, l = T & 63;
    int n = tk / 3, ks = tk - n * 3;
    int o = n * 16 + (l & 15);
    const float* src = fc1_w + o * 96 + ks * 32 + (l >> 4) * 8;
    uint4 d;
    d.x = packb(src[0], src[1]); d.y = packb(src[2], src[3]);
    d.z = packb(src[4], src[5]); d.w = packb(src[6], src[7]);
    *(uint4*)&w1f[(size_t)(tk * 64 + l) * 4] = d;
    return;
  }
  T -= 4608;
  if (T < 4608) {  // fc2: 6 n-tiles x 12 k-steps
    int tk = T >> 6, l = T & 63;
    int n = tk / 12, ks = tk - n * 12;
    int o = n * 16 + (l & 15);
    const float* src = fc2_w + o * 384 + ks * 32 + (l >> 4) * 8;
    uint4 d;
    d.x = packb(src[0], src[1]); d.y = packb(src[2], src[3]);
    d.z = packb(src[4], src[5]); d.w = packb(src[6], src[7]);
    *(uint4*)&w2f[(size_t)(tk * 64 + l) * 4] = d;
    return;
  }
  T -= 4608;
  if (T < 9216) {  // proj transpose (for proj_ln kernel, unchanged layout)
    int k = T / 96, c = T - k * 96;
    pwT[T] = f2b(proj_w[c * 96 + k]);
  }
}

// ---------------- P1: CPB MLP table (169 x 3) --------------------------------
__global__ __launch_bounds__(512) void cpb_table_kernel(
    const float* __restrict__ w1, const float* __restrict__ b1,
    const float* __restrict__ w2, float* __restrict__ tabout) {
  int tid = threadIdx.x;
  if (tid >= 169 * 3) return;
  int e = tid / 3, h = tid - e * 3;
  int i = e / 13, j = e - i * 13;
  float ti = (float)(i - 6) * (8.0f / 6.0f);
  float tj = (float)(j - 6) * (8.0f / 6.0f);
  float sx = (ti > 0.f) ? 1.f : (ti < 0.f ? -1.f : 0.f);
  float sy = (tj > 0.f) ? 1.f : (tj < 0.f ? -1.f : 0.f);
  float tx = sx * log2f(fabsf(ti) + 1.f) * (1.0f / 3.0f);
  float ty = sy * log2f(fabsf(tj) + 1.f) * (1.0f / 3.0f);
  float acc = 0.f;
  for (int jj = 0; jj < 512; ++jj) {
    float hv = tx * w1[jj * 2 + 0] + ty * w1[jj * 2 + 1] + b1[jj];
    float g = 0.5f * hv * (1.f + erff(hv * 0.70710678118654752f));
    acc += g * w2[h * 512 + jj];
  }
  tabout[e * 3 + h] = acc;
}

// ---------------- P2: 16*sigmoid(rpb) gathered to (3,49,49) ------------------
__global__ __launch_bounds__(256) void bias_kernel(
    const float* __restrict__ tabout, float* __restrict__ bias16) {
  int idx = blockIdx.x * 256 + threadIdx.x;
  if (idx >= NHEADS * NTOK * NTOK) return;
  int h = idx / (NTOK * NTOK);
  int rem = idx - h * NTOK * NTOK;
  int i = rem / NTOK, j = rem - i * NTOK;
  int ri = (i / WSZ) - (j / WSZ) + 6;
  int ci = (i % WSZ) - (j % WSZ) + 6;
  int e = ri * 13 + ci;
  float v = tabout[e * 3 + h];
  bias16[idx] = 16.f / (1.f + expf(-v));
}

// ---------------- K1: token-major QKV GEMM (MFMA) + cosine norm --------------
// M=64 tokens/block, 4 waves; wave w owns M-tile w. Outputs bf16 [tok][h][32].
__global__ __launch_bounds__(256) void qkv_mfma_kernel(
    const float* __restrict__ x, const unsigned* __restrict__ qkvf,
    const float* __restrict__ q_bias, const float* __restrict__ v_bias,
    const float* __restrict__ logit_scale,
    unsigned* __restrict__ qws, unsigned* __restrict__ kws,
    unsigned* __restrict__ vws) {
  __shared__ unsigned xa[64 * 52];   // [64 tok][104 bf16] padded
  int tid = threadIdx.x, lane = tid & 63, wv = tid >> 6;
  size_t tok0 = (size_t)blockIdx.x * 64;

  for (int idx = tid; idx < 3072; idx += 256) {
    int t = idx / 48, c2 = idx - t * 48;
    const float2 s = *(const float2*)(x + (tok0 + t) * 96 + c2 * 2);
    xa[t * 52 + c2] = packb(s.x, s.y);
  }
  __syncthreads();

  int c15 = lane & 15, q4 = lane >> 4;
  bf16x8 afr[3];
  #pragma unroll
  for (int k = 0; k < 3; ++k)
    afr[k] = *(const bf16x8*)&xa[(wv * 16 + c15) * 52 + k * 16 + q4 * 4];

  f32x4 acc[18];
  #pragma unroll
  for (int n = 0; n < 18; ++n) acc[n] = f32x4{0.f, 0.f, 0.f, 0.f};
  #pragma unroll
  for (int n = 0; n < 18; ++n) {
    #pragma unroll
    for (int k = 0; k < 3; ++k) {
      bf16x8 b = *(const bf16x8*)&qkvf[(size_t)((n * 3 + k) * 64 + lane) * 4];
      acc[n] = mfma16(afr[k], b, acc[n]);
    }
  }

  // epilogue: C layout col=lane&15, row=(lane>>4)*4+i
  int tokr0 = (int)tok0 + wv * 16 + q4 * 4;
  #pragma unroll
  for (int h = 0; h < 3; ++h) {
    float sc = expf(fminf(logit_scale[h], LN100));
    // ---- q (tiles 2h, 2h+1): cosine norm + temperature ----
    {
      f32x4 a0 = acc[2 * h], a1 = acc[2 * h + 1];
      float b0 = q_bias[h * 32 + c15], b1 = q_bias[h * 32 + 16 + c15];
      unsigned pk[8];
      #pragma unroll
      for (int i = 0; i < 4; ++i) {
        float va = a0[i] + b0, vb = a1[i] + b1;
        float ss = va * va + vb * vb;
        ss += __shfl_xor(ss, 1, 64); ss += __shfl_xor(ss, 2, 64);
        ss += __shfl_xor(ss, 4, 64); ss += __shfl_xor(ss, 8, 64);
        float inv = sc / fmaxf(sqrtf(ss), 1e-12f);
        va *= inv; vb *= inv;
        float pa = __shfl_xor(va, 1, 64), pb = __shfl_xor(vb, 1, 64);
        pk[i] = packb(va, pa); pk[4 + i] = packb(vb, pb);
      }
      if (!(lane & 1)) {
        int dw0 = c15 >> 1;
        #pragma unroll
        for (int i = 0; i < 4; ++i) {
          size_t base = ((size_t)(tokr0 + i) * 3 + h) * 16;
          qws[base + dw0] = pk[i];
          qws[base + 8 + dw0] = pk[4 + i];
        }
      }
    }
    // ---- k (tiles 6+2h, 7+2h): cosine norm, zero bias ----
    {
      f32x4 a0 = acc[6 + 2 * h], a1 = acc[7 + 2 * h];
      unsigned pk[8];
      #pragma unroll
      for (int i = 0; i < 4; ++i) {
        float va = a0[i], vb = a1[i];
        float ss = va * va + vb * vb;
        ss += __shfl_xor(ss, 1, 64); ss += __shfl_xor(ss, 2, 64);
        ss += __shfl_xor(ss, 4, 64); ss += __shfl_xor(ss, 8, 64);
        float inv = 1.f / fmaxf(sqrtf(ss), 1e-12f);
        va *= inv; vb *= inv;
        float pa = __shfl_xor(va, 1, 64), pb = __shfl_xor(vb, 1, 64);
        pk[i] = packb(va, pa); pk[4 + i] = packb(vb, pb);
      }
      if (!(lane & 1)) {
        int dw0 = c15 >> 1;
        #pragma unroll
        for (int i = 0; i < 4; ++i) {
          size_t base = ((size_t)(tokr0 + i) * 3 + h) * 16;
          kws[base + dw0] = pk[i];
          kws[base + 8 + dw0] = pk[4 + i];
        }
      }
    }
    // ---- v (tiles 12+2h, 13+2h): bias only ----
    {
      f32x4 a0 = acc[12 + 2 * h], a1 = acc[13 + 2 * h];
      float b0 = v_bias[h * 32 + c15], b1 = v_bias[h * 32 + 16 + c15];
      unsigned pk[8];
      #pragma unroll
      for (int i = 0; i < 4; ++i) {
        float va = a0[i] + b0, vb = a1[i] + b1;
        float pa = __shfl_xor(va, 1, 64), pb = __shfl_xor(vb, 1, 64);
        pk[i] = packb(va, pa); pk[4 + i] = packb(vb, pb);
      }
      if (!(lane & 1)) {
        int dw0 = c15 >> 1;
        #pragma unroll
        for (int i = 0; i < 4; ++i) {
          size_t base = ((size_t)(tokr0 + i) * 3 + h) * 16;
          vws[base + dw0] = pk[i];
          vws[base + 8 + dw0] = pk[4 + i];
        }
      }
    }
  }
}

// ---------------- K2: per-(window,head) attention core -----------------------
__global__ __launch_bounds__(128) void attn_core_kernel(
    const unsigned* __restrict__ qws, const unsigned* __restrict__ kws,
    const unsigned* __restrict__ vws, const float* __restrict__ bias16,
    const float* __restrict__ mask, unsigned* __restrict__ aout) {
  int blk = blockIdx.x;
  int win = blk / 3, h = blk - win * 3;
  int b = win >> 6, wi = win & 63, wh = wi >> 3, wcx = wi & 7;
  __shared__ unsigned qs[833], ks[833], vs[784];
  __shared__ float P[49 * 53];
  int tid = threadIdx.x;
  for (int idx = tid; idx < 784; idx += 128) {
    int t = idx >> 4, d2 = idx & 15;
    int tr = (t * 9363) >> 16;           // t/7 for t<49
    int tc = t - tr * 7;
    int R = wh * 7 + tr + SHIFT_; if (R >= HW) R -= HW;
    int C = wcx * 7 + tc + SHIFT_; if (C >= HW) C -= HW;
    size_t tok = (size_t)b * 3136 + R * 56 + C;
    size_t base = (tok * 3 + h) * 16;
    qs[t * 17 + d2] = qws[base + d2];
    ks[t * 17 + d2] = kws[base + d2];
    vs[t * 16 + d2] = vws[base + d2];
  }
  __syncthreads();

  const float* bsl = bias16 + h * 2401;
  const float* msl = mask + (size_t)wi * 2401;
  for (int task = tid; task < 343; task += 128) {
    int i = task / 7, j0 = (task - i * 7) * 7;
    float acc[7] = {0, 0, 0, 0, 0, 0, 0};
    for (int d2 = 0; d2 < 16; ++d2) {
      unsigned qv = qs[i * 17 + d2];
      float q0 = blo(qv), q1 = bhi(qv);
      #pragma unroll
      for (int jj = 0; jj < 7; ++jj) {
        unsigned kv = ks[(j0 + jj) * 17 + d2];
        acc[jj] += q0 * blo(kv) + q1 * bhi(kv);
      }
    }
    #pragma unroll
    for (int jj = 0; jj < 7; ++jj) {
      int j = j0 + jj;
      P[i * 53 + j] = acc[jj] + bsl[i * 49 + j] + msl[i * 49 + j];
    }
  }
  __syncthreads();

  if (tid < 49) {
    float* row = P + tid * 53;
    float mx = -1e30f;
    for (int j = 0; j < 49; ++j) mx = fmaxf(mx, row[j]);
    float s = 0.f;
    for (int j = 0; j < 49; ++j) { float e = expf(row[j] - mx); row[j] = e; s += e; }
    float inv = 1.f / s;
    for (int j = 0; j < 49; ++j) row[j] *= inv;
  }
  __syncthreads();

  for (int task = tid; task < 196; task += 128) {
    int t = task >> 2, dg = task & 3;
    float acc[8] = {0, 0, 0, 0, 0, 0, 0, 0};
    for (int j = 0; j < 49; ++j) {
      float p = P[t * 53 + j];
      uint4 vv = *(const uint4*)&vs[j * 16 + dg * 4];
      float vf[8]; unp8(vv, vf);
      #pragma unroll
      for (int oo = 0; oo < 8; ++oo) acc[oo] += p * vf[oo];
    }
    uint4 o4;
    o4.x = packb(acc[0], acc[1]); o4.y = packb(acc[2], acc[3]);
    o4.z = packb(acc[4], acc[5]); o4.w = packb(acc[6], acc[7]);
    *(uint4*)&aout[(((size_t)win * 49 + t)) * 48 + h * 16 + dg * 4] = o4;
  }
}

// ---------------- K3: proj + LN1 + residual ----------------------------------
__global__ __launch_bounds__(256) void proj_ln_kernel(
    const unsigned* __restrict__ aout, const unsigned* __restrict__ pwT_u,
    const float* __restrict__ proj_b, const float* __restrict__ x,
    const float* __restrict__ n1g, const float* __restrict__ n1b,
    float* __restrict__ out) {
  __shared__ unsigned pw[4608];
  __shared__ unsigned at[32 * 49];
  __shared__ float yb[32 * 97];
  __shared__ float mu_s[32], rs_s[32];
  int tid = threadIdx.x;
  int wt0 = blockIdx.x * 32;
  for (int idx = tid; idx < 4608; idx += 256) pw[idx] = pwT_u[idx];
  for (int idx = tid; idx < 1536; idx += 256) {
    int t = idx / 48, k2 = idx - t * 48;
    at[t * 49 + k2] = aout[(size_t)wt0 * 48 + idx];
  }
  __syncthreads();

  int cg = tid % 12, tg = tid / 12;
  if (tg < 16) {
    int t0 = tg * 2, c0 = cg * 8;
    float acc[2][8] = {};
    for (int k2 = 0; k2 < 48; ++k2) {
      unsigned a0 = at[t0 * 49 + k2], a1 = at[(t0 + 1) * 49 + k2];
      uint4 w0 = *(const uint4*)&pw[(2 * k2) * 48 + cg * 4];
      uint4 w1 = *(const uint4*)&pw[(2 * k2) * 48 + 48 + cg * 4];
      float wl[8], wh2[8]; unp8(w0, wl); unp8(w1, wh2);
      float a00 = blo(a0), a01 = bhi(a0), a10 = blo(a1), a11 = bhi(a1);
      #pragma unroll
      for (int oo = 0; oo < 8; ++oo) {
        acc[0][oo] += a00 * wl[oo] + a01 * wh2[oo];
        acc[1][oo] += a10 * wl[oo] + a11 * wh2[oo];
      }
    }
    #pragma unroll
    for (int tt = 0; tt < 2; ++tt)
      #pragma unroll
      for (int oo = 0; oo < 8; ++oo)
        yb[(t0 + tt) * 97 + c0 + oo] = acc[tt][oo] + proj_b[c0 + oo];
  }
  __syncthreads();

  if (tid < 32) {
    const float* row = yb + tid * 97;
    float mu = 0.f;
    for (int c = 0; c < 96; ++c) mu += row[c];
    mu *= (1.f / 96.f);
    float var = 0.f;
    for (int c = 0; c < 96; ++c) { float d = row[c] - mu; var += d * d; }
    var *= (1.f / 96.f);
    mu_s[tid] = mu;
    rs_s[tid] = rsqrtf(var + 1e-5f);
  }
  __syncthreads();

  for (int idx = tid; idx < 3072; idx += 256) {
    int t = idx / 96, c = idx - t * 96;
    int wt = wt0 + t;
    int win = wt / 49, tt2 = wt - win * 49;
    int b = win >> 6, wi = win & 63, wh = wi >> 3, wcx = wi & 7;
    int tr = tt2 / 7, tc = tt2 - tr * 7;
    int R = wh * 7 + tr + SHIFT_; if (R >= HW) R -= HW;
    int C = wcx * 7 + tc + SHIFT_; if (C >= HW) C -= HW;
    size_t orig = ((size_t)(b * 3136 + R * 56 + C)) * 96 + c;
    out[orig] = x[orig] + (yb[t * 97 + c] - mu_s[t]) * rs_s[t] * n1g[c] + n1b[c];
  }
}

// ---------------- K4: MLP via MFMA + LN2 + residual (in-place) ---------------
__global__ __launch_bounds__(256) void mlp_mfma_kernel(
    const unsigned* __restrict__ w1f, const float* __restrict__ fc1_b,
    const unsigned* __restrict__ w2f, const float* __restrict__ fc2_b,
    const float* __restrict__ n2g, const float* __restrict__ n2b,
    float* __restrict__ xio) {
  __shared__ unsigned xa[64 * 52];       // 13312 B: x1 bf16 [64][104]
  __shared__ unsigned hid[64 * 196];     // 50176 B: hidden bf16 [64][392] / ybuf f32
  __shared__ float mu_s[64], rs_s[64];
  int tid = threadIdx.x, lane = tid & 63, wv = tid >> 6;
  int c15 = lane & 15, q4 = lane >> 4;
  size_t tok0 = (size_t)blockIdx.x * 64;

  for (int idx = tid; idx < 3072; idx += 256) {
    int t = idx / 48, c2 = idx - t * 48;
    const float2 s = *(const float2*)(xio + (tok0 + t) * 96 + c2 * 2);
    xa[t * 52 + c2] = packb(s.x, s.y);
  }
  __syncthreads();

  // ---- fc1: wave wv -> N-tiles 6wv..6wv+5, all 4 M-tiles ----
  bf16x8 afr[4][3];
  #pragma unroll
  for (int m = 0; m < 4; ++m)
    #pragma unroll
    for (int k = 0; k < 3; ++k)
      afr[m][k] = *(const bf16x8*)&xa[(m * 16 + c15) * 52 + k * 16 + q4 * 4];
  f32x4 acc[4][6];
  #pragma unroll
  for (int m = 0; m < 4; ++m)
    #pragma unroll
    for (int n = 0; n < 6; ++n) acc[m][n] = f32x4{0.f, 0.f, 0.f, 0.f};
  #pragma unroll
  for (int n = 0; n < 6; ++n) {
    #pragma unroll
    for (int k = 0; k < 3; ++k) {
      bf16x8 b = *(const bf16x8*)&w1f[(size_t)(((6 * wv + n) * 3 + k) * 64 + lane) * 4];
      #pragma unroll
      for (int m = 0; m < 4; ++m) acc[m][n] = mfma16(afr[m][k], b, acc[m][n]);
    }
  }
  // GELU -> hid (bf16, padded stride 392)
  unsigned short* hidb = (unsigned short*)hid;
  #pragma unroll
  for (int n = 0; n < 6; ++n) {
    int col = (6 * wv + n) * 16 + c15;
    float bo = fc1_b[col];
    #pragma unroll
    for (int m = 0; m < 4; ++m) {
      #pragma unroll
      for (int i = 0; i < 4; ++i) {
        float v = acc[m][n][i] + bo;
        float g = 0.5f * v * (1.f + erff(v * 0.70710678118654752f));
        hidb[(m * 16 + q4 * 4 + i) * 392 + col] = f2b(g);
      }
    }
  }
  __syncthreads();

  // ---- fc2: wave wv -> M-tile wv, 6 N-tiles, 12 K-steps ----
  f32x4 acc2[6];
  #pragma unroll
  for (int n = 0; n < 6; ++n) acc2[n] = f32x4{0.f, 0.f, 0.f, 0.f};
  #pragma unroll
  for (int k = 0; k < 12; ++k) {
    bf16x8 a = *(const bf16x8*)&hid[(wv * 16 + c15) * 196 + k * 16 + q4 * 4];
    #pragma unroll
    for (int n = 0; n < 6; ++n) {
      bf16x8 b = *(const bf16x8*)&w2f[(size_t)((n * 12 + k) * 64 + lane) * 4];
      acc2[n] = mfma16(a, b, acc2[n]);
    }
  }
  __syncthreads();   // all hid reads done before reuse as ybuf

  float* ybuf = (float*)hid;   // [64][100] f32 = 25600 B
  #pragma unroll
  for (int n = 0; n < 6; ++n) {
    int col = n * 16 + c15;
    float bo = fc2_b[col];
    #pragma unroll
    for (int i = 0; i < 4; ++i)
      ybuf[(wv * 16 + q4 * 4 + i) * 100 + col] = acc2[n][i] + bo;
  }
  __syncthreads();

  // LN2 stats: 4 threads/token
  {
    int t = tid >> 2, p = tid & 3;
    const float* row = ybuf + t * 100 + p * 24;
    float s = 0.f, s2 = 0.f;
    for (int c = 0; c < 24; ++c) { float v = row[c]; s += v; s2 += v * v; }
    s += __shfl_xor(s, 1, 64); s2 += __shfl_xor(s2, 1, 64);
    s += __shfl_xor(s, 2, 64); s2 += __shfl_xor(s2, 2, 64);
    if (p == 0) {
      float mu = s * (1.f / 96.f);
      float var = s2 * (1.f / 96.f) - mu * mu;
      mu_s[t] = mu;
      rs_s[t] = rsqrtf(fmaxf(var, 0.f) + 1e-5f);
    }
  }
  __syncthreads();

  for (int idx = tid; idx < 6144; idx += 256) {
    int t = idx / 96, c = idx - t * 96;
    float y = ybuf[t * 100 + c];
    xio[tok0 * 96 + idx] += (y - mu_s[t]) * rs_s[t] * n2g[c] + n2b[c];
  }
}

// ---------------- launch ------------------------------------------------------
extern "C" void kernel_launch(void* const* d_in, const int* in_sizes, int n_in,
                              void* d_out, int out_size, void* d_ws, size_t ws_size,
                              hipStream_t stream) {
  const float* x           = (const float*)d_in[0];
  const float* attn_mask   = (const float*)d_in[1];
  const float* qkv_w       = (const float*)d_in[2];
  const float* q_bias      = (const float*)d_in[3];
  const float* v_bias      = (const float*)d_in[4];
  const float* logit_scale = (const float*)d_in[5];
  const float* cpb_w1      = (const float*)d_in[6];
  const float* cpb_b1      = (const float*)d_in[7];
  const float* cpb_w2      = (const float*)d_in[8];
  const float* proj_w      = (const float*)d_in[9];
  const float* proj_b      = (const float*)d_in[10];
  const float* n1g         = (const float*)d_in[11];
  const float* n1b         = (const float*)d_in[12];
  const float* fc1_w       = (const float*)d_in[13];
  const float* fc1_b       = (const float*)d_in[14];
  const float* fc2_w       = (const float*)d_in[15];
  const float* fc2_b       = (const float*)d_in[16];
  const float* n2g         = (const float*)d_in[17];
  const float* n2b         = (const float*)d_in[18];
  float* out = (float*)d_out;

  // ---- workspace layout ----
  float* bias16 = (float*)d_ws;                          // 7296 f32
  float* tab    = bias16 + 7296;                         // 512 f32
  unsigned* qkvf = (unsigned*)(tab + 512);               // 13824 dw
  unsigned* w1f  = qkvf + 13824;                         // 18432 dw
  unsigned* w2f  = w1f + 18432;                          // 18432 dw
  unsigned short* pwT = (unsigned short*)(w2f + 18432);  // 9216 bf16
  unsigned* qws  = (unsigned*)(pwT + 9216);              // 9,633,792 dw each
  unsigned* kws  = qws + 9633792;
  unsigned* vws  = kws + 9633792;
  unsigned* aout = vws + 9633792;

  wconv2_kernel<<<87, 256, 0, stream>>>(qkv_w, fc1_w, fc2_w, proj_w,
                                        qkvf, w1f, w2f, pwT);
  cpb_table_kernel<<<1, 512, 0, stream>>>(cpb_w1, cpb_b1, cpb_w2, tab);
  bias_kernel<<<(NHEADS * NTOK * NTOK + 255) / 256, 256, 0, stream>>>(tab, bias16);
  qkv_mfma_kernel<<<NTOKENS / 64, 256, 0, stream>>>(x, qkvf, q_bias, v_bias,
                                                    logit_scale, qws, kws, vws);
  attn_core_kernel<<<NWIN_TOT * 3, 128, 0, stream>>>(qws, kws, vws, bias16,
                                                     attn_mask, aout);
  proj_ln_kernel<<<NTOKENS / 32, 256, 0, stream>>>(aout, (const unsigned*)pwT,
                                                   proj_b, x, n1g, n1b, out);
  mlp_mfma_kernel<<<NTOKENS / 64, 256, 0, stream>>>(w1f, fc1_b, w2f, fc2_b,
                                                    n2g, n2b, out);
}

// Round 6
// 531.867 us; speedup vs baseline: 9.4027x; 1.6512x over previous
//
#include <hip/hip_runtime.h>
#include <math.h>

#define BATCH 64
#define HW 56
#define CDIM 96
#define NHEADS 3
#define WSZ 7
#define NTOK 49
#define SHIFT_ 3
#define NWIN_TOT 4096
#define HID 384
#define NTOKENS (BATCH * HW * HW)   // 200704
#define LN100 4.6051702f

typedef __attribute__((ext_vector_type(8))) short bf16x8;
typedef __attribute__((ext_vector_type(4))) float f32x4;

__device__ inline f32x4 mfma16(bf16x8 a, bf16x8 b, f32x4 c) {
  return __builtin_amdgcn_mfma_f32_16x16x32_bf16(a, b, c, 0, 0, 0);
}

// ---------- bf16 helpers ----------
__device__ inline unsigned short f2b(float f) {
  unsigned u = __float_as_uint(f);
  unsigned r = (u + 0x7FFFu + ((u >> 16) & 1u)) >> 16;
  return (unsigned short)r;
}
__device__ inline float blo(unsigned u) { return __uint_as_float(u << 16); }
__device__ inline unsigned packb(float a, float b) {
  return (unsigned)f2b(a) | ((unsigned)f2b(b) << 16);
}
// split f32 -> (hi, lo) bf16 fragments: hi+lo reproduces p to ~2^-18
__device__ inline void split8(const float* p, bf16x8& hi, bf16x8& lo) {
  short h8[8], l8[8];
  #pragma unroll
  for (int j = 0; j < 8; ++j) {
    unsigned short h = f2b(p[j]);
    float hf = __uint_as_float((unsigned)h << 16);
    h8[j] = (short)h;
    l8[j] = (short)f2b(p[j] - hf);
  }
  hi = bf16x8{h8[0], h8[1], h8[2], h8[3], h8[4], h8[5], h8[6], h8[7]};
  lo = bf16x8{l8[0], l8[1], l8[2], l8[3], l8[4], l8[5], l8[6], l8[7]};
}

// ---------------- P0: weight conversion into MFMA B-frag layouts --------------
__global__ __launch_bounds__(256) void wconv2_kernel(
    const float* __restrict__ qkv_w, const float* __restrict__ fc1_w,
    const float* __restrict__ fc2_w, const float* __restrict__ proj_w,
    unsigned* __restrict__ qkvf, unsigned* __restrict__ w1f,
    unsigned* __restrict__ w2f, unsigned* __restrict__ pwf) {
  int T = blockIdx.x * 256 + threadIdx.x;
  if (T < 3456) {  // qkv: 18 n-tiles x 3 k-steps
    int tk = T >> 6, l = T & 63;
    int n = tk / 3, ks = tk - n * 3;
    int o = n * 16 + (l & 15);
    const float* src = qkv_w + o * 96 + ks * 32 + (l >> 4) * 8;
    uint4 d;
    d.x = packb(src[0], src[1]); d.y = packb(src[2], src[3]);
    d.z = packb(src[4], src[5]); d.w = packb(src[6], src[7]);
    *(uint4*)&qkvf[(size_t)(tk * 64 + l) * 4] = d;
    return;
  }
  T -= 3456;
  if (T < 4608) {  // fc1
    int tk = T >> 6, l = T & 63;
    int n = tk / 3, ks = tk - n * 3;
    int o = n * 16 + (l & 15);
    const float* src = fc1_w + o * 96 + ks * 32 + (l >> 4) * 8;
    uint4 d;
    d.x = packb(src[0], src[1]); d.y = packb(src[2], src[3]);
    d.z = packb(src[4], src[5]); d.w = packb(src[6], src[7]);
    *(uint4*)&w1f[(size_t)(tk * 64 + l) * 4] = d;
    return;
  }
  T -= 4608;
  if (T < 4608) {  // fc2
    int tk = T >> 6, l = T & 63;
    int n = tk / 12, ks = tk - n * 12;
    int o = n * 16 + (l & 15);
    const float* src = fc2_w + o * 384 + ks * 32 + (l >> 4) * 8;
    uint4 d;
    d.x = packb(src[0], src[1]); d.y = packb(src[2], src[3]);
    d.z = packb(src[4], src[5]); d.w = packb(src[6], src[7]);
    *(uint4*)&w2f[(size_t)(tk * 64 + l) * 4] = d;
    return;
  }
  T -= 4608;
  if (T < 1152) {  // proj
    int tk = T >> 6, l = T & 63;
    int n = tk / 3, ks = tk - n * 3;
    int o = n * 16 + (l & 15);
    const float* src = proj_w + o * 96 + ks * 32 + (l >> 4) * 8;
    uint4 d;
    d.x = packb(src[0], src[1]); d.y = packb(src[2], src[3]);
    d.z = packb(src[4], src[5]); d.w = packb(src[6], src[7]);
    *(uint4*)&pwf[(size_t)(tk * 64 + l) * 4] = d;
  }
}

// ---------------- P1: CPB MLP table raw (169 x 3), as round 3 -----------------
__global__ __launch_bounds__(512) void cpb_table_kernel(
    const float* __restrict__ w1, const float* __restrict__ b1,
    const float* __restrict__ w2, float* __restrict__ tabout) {
  int tid = threadIdx.x;
  if (tid >= 169 * 3) return;
  int e = tid / 3, h = tid - e * 3;
  int i = e / 13, j = e - i * 13;
  float ti = (float)(i - 6) * (8.0f / 6.0f);
  float tj = (float)(j - 6) * (8.0f / 6.0f);
  float sx = (ti > 0.f) ? 1.f : (ti < 0.f ? -1.f : 0.f);
  float sy = (tj > 0.f) ? 1.f : (tj < 0.f ? -1.f : 0.f);
  float tx = sx * log2f(fabsf(ti) + 1.f) * (1.0f / 3.0f);
  float ty = sy * log2f(fabsf(tj) + 1.f) * (1.0f / 3.0f);
  float acc = 0.f;
  for (int jj = 0; jj < 512; ++jj) {
    float hv = tx * w1[jj * 2 + 0] + ty * w1[jj * 2 + 1] + b1[jj];
    float g = 0.5f * hv * (1.f + erff(hv * 0.70710678118654752f));
    acc += g * w2[h * 512 + jj];
  }
  tabout[e * 3 + h] = acc;
}

// ---------------- P2: 16*sigmoid(rpb) gathered to (3,49,49), as round 3 -------
__global__ __launch_bounds__(256) void bias_kernel(
    const float* __restrict__ tabout, float* __restrict__ bias16) {
  int idx = blockIdx.x * 256 + threadIdx.x;
  if (idx >= NHEADS * NTOK * NTOK) return;
  int h = idx / (NTOK * NTOK);
  int rem = idx - h * NTOK * NTOK;
  int i = rem / NTOK, j = rem - i * NTOK;
  int ri = (i / WSZ) - (j / WSZ) + 6;
  int ci = (i % WSZ) - (j % WSZ) + 6;
  int e = ri * 13 + ci;
  float v = tabout[e * 3 + h];
  bias16[idx] = 16.f / (1.f + expf(-v));
}

// ---------------- K1: token-major QKV GEMM (MFMA) + cosine norm (r3, passed) --
__global__ __launch_bounds__(256) void qkv_mfma_kernel(
    const float* __restrict__ x, const unsigned* __restrict__ qkvf,
    const float* __restrict__ q_bias, const float* __restrict__ v_bias,
    const float* __restrict__ logit_scale,
    unsigned* __restrict__ qws, unsigned* __restrict__ kws,
    unsigned* __restrict__ vws) {
  __shared__ unsigned xa[64 * 52];
  int tid = threadIdx.x, lane = tid & 63, wv = tid >> 6;
  size_t tok0 = (size_t)blockIdx.x * 64;

  for (int idx = tid; idx < 3072; idx += 256) {
    int t = idx / 48, c2 = idx - t * 48;
    const float2 s = *(const float2*)(x + (tok0 + t) * 96 + c2 * 2);
    xa[t * 52 + c2] = packb(s.x, s.y);
  }
  __syncthreads();

  int c15 = lane & 15, q4 = lane >> 4;
  bf16x8 afr[3];
  #pragma unroll
  for (int k = 0; k < 3; ++k)
    afr[k] = *(const bf16x8*)&xa[(wv * 16 + c15) * 52 + k * 16 + q4 * 4];

  f32x4 acc[18];
  #pragma unroll
  for (int n = 0; n < 18; ++n) acc[n] = f32x4{0.f, 0.f, 0.f, 0.f};
  #pragma unroll
  for (int n = 0; n < 18; ++n) {
    #pragma unroll
    for (int k = 0; k < 3; ++k) {
      bf16x8 b = *(const bf16x8*)&qkvf[(size_t)((n * 3 + k) * 64 + lane) * 4];
      acc[n] = mfma16(afr[k], b, acc[n]);
    }
  }

  int tokr0 = (int)tok0 + wv * 16 + q4 * 4;
  #pragma unroll
  for (int h = 0; h < 3; ++h) {
    float sc = expf(fminf(logit_scale[h], LN100));
    {   // q
      f32x4 a0 = acc[2 * h], a1 = acc[2 * h + 1];
      float b0 = q_bias[h * 32 + c15], b1 = q_bias[h * 32 + 16 + c15];
      unsigned pk[8];
      #pragma unroll
      for (int i = 0; i < 4; ++i) {
        float va = a0[i] + b0, vb = a1[i] + b1;
        float ss = va * va + vb * vb;
        ss += __shfl_xor(ss, 1, 64); ss += __shfl_xor(ss, 2, 64);
        ss += __shfl_xor(ss, 4, 64); ss += __shfl_xor(ss, 8, 64);
        float inv = sc / fmaxf(sqrtf(ss), 1e-12f);
        va *= inv; vb *= inv;
        float pa = __shfl_xor(va, 1, 64), pb = __shfl_xor(vb, 1, 64);
        pk[i] = packb(va, pa); pk[4 + i] = packb(vb, pb);
      }
      if (!(lane & 1)) {
        int dw0 = c15 >> 1;
        #pragma unroll
        for (int i = 0; i < 4; ++i) {
          size_t base = ((size_t)(tokr0 + i) * 3 + h) * 16;
          qws[base + dw0] = pk[i];
          qws[base + 8 + dw0] = pk[4 + i];
        }
      }
    }
    {   // k
      f32x4 a0 = acc[6 + 2 * h], a1 = acc[7 + 2 * h];
      unsigned pk[8];
      #pragma unroll
      for (int i = 0; i < 4; ++i) {
        float va = a0[i], vb = a1[i];
        float ss = va * va + vb * vb;
        ss += __shfl_xor(ss, 1, 64); ss += __shfl_xor(ss, 2, 64);
        ss += __shfl_xor(ss, 4, 64); ss += __shfl_xor(ss, 8, 64);
        float inv = 1.f / fmaxf(sqrtf(ss), 1e-12f);
        va *= inv; vb *= inv;
        float pa = __shfl_xor(va, 1, 64), pb = __shfl_xor(vb, 1, 64);
        pk[i] = packb(va, pa); pk[4 + i] = packb(vb, pb);
      }
      if (!(lane & 1)) {
        int dw0 = c15 >> 1;
        #pragma unroll
        for (int i = 0; i < 4; ++i) {
          size_t base = ((size_t)(tokr0 + i) * 3 + h) * 16;
          kws[base + dw0] = pk[i];
          kws[base + 8 + dw0] = pk[4 + i];
        }
      }
    }
    {   // v
      f32x4 a0 = acc[12 + 2 * h], a1 = acc[13 + 2 * h];
      float b0 = v_bias[h * 32 + c15], b1 = v_bias[h * 32 + 16 + c15];
      unsigned pk[8];
      #pragma unroll
      for (int i = 0; i < 4; ++i) {
        float va = a0[i] + b0, vb = a1[i] + b1;
        float pa = __shfl_xor(va, 1, 64), pb = __shfl_xor(vb, 1, 64);
        pk[i] = packb(va, pa); pk[4 + i] = packb(vb, pb);
      }
      if (!(lane & 1)) {
        int dw0 = c15 >> 1;
        #pragma unroll
        for (int i = 0; i < 4; ++i) {
          size_t base = ((size_t)(tokr0 + i) * 3 + h) * 16;
          vws[base + dw0] = pk[i];
          vws[base + 8 + dw0] = pk[4 + i];
        }
      }
    }
  }
}

// ---------------- K2: fused attention + proj + LN1 (r3 numerics) --------------
__global__ __launch_bounds__(256) void attn_fused_kernel(
    const unsigned* __restrict__ qws, const unsigned* __restrict__ kws,
    const unsigned* __restrict__ vws, const float* __restrict__ bias16,
    const float* __restrict__ mask, const unsigned* __restrict__ pwf,
    const float* __restrict__ proj_b, const float* __restrict__ x,
    const float* __restrict__ n1g, const float* __restrict__ n1b,
    float* __restrict__ out) {
  __shared__ int toks[64];                     //   256 B
  __shared__ unsigned short VtS[3 * 32 * 72];  // 13824 B
  __shared__ float Pf[3 * 64 * 68];            // 52224 B; later ybuf f32[64][100]
  __shared__ unsigned obuf[64 * 52];           // 13312 B
  // total ~79.6 KB -> 2 blocks/CU

  int tid = threadIdx.x, lane = tid & 63, wv = tid >> 6;
  int c15 = lane & 15, q4 = lane >> 4;
  int win = blockIdx.x;
  int b = win >> 6, wi = win & 63, wh = wi >> 3, wcx = wi & 7;

  if (tid < 64) {
    int t = tid < 49 ? tid : 48;
    int tr = (t * 9363) >> 16, tc = t - tr * 7;
    int R = wh * 7 + tr + SHIFT_; if (R >= HW) R -= HW;
    int C = wcx * 7 + tc + SHIFT_; if (C >= HW) C -= HW;
    toks[tid] = b * 3136 + R * 56 + C;
  }
  for (int i = tid; i < 3456; i += 256) ((unsigned*)VtS)[i] = 0u;
  __syncthreads();

  // stage V transposed
  for (int idx = tid; idx < 2352; idx += 256) {
    int h2 = idx / 784, rem = idx - h2 * 784;
    int t = rem >> 4, d2 = rem & 15;
    unsigned v = vws[((size_t)toks[t] * 3 + h2) * 16 + d2];
    VtS[h2 * 2304 + (2 * d2) * 72 + t] = (unsigned short)(v & 0xFFFFu);
    VtS[h2 * 2304 + (2 * d2 + 1) * 72 + t] = (unsigned short)(v >> 16);
  }
  __syncthreads();

  if (wv < 3) {
    int h = wv;
    bf16x8 qf[4], kf[4];
    #pragma unroll
    for (int m = 0; m < 4; ++m)
      qf[m] = *(const bf16x8*)&qws[((size_t)toks[m * 16 + c15] * 3 + h) * 16 + q4 * 4];
    #pragma unroll
    for (int n = 0; n < 4; ++n)
      kf[n] = *(const bf16x8*)&kws[((size_t)toks[n * 16 + c15] * 3 + h) * 16 + q4 * 4];

    f32x4 s[4][4];
    #pragma unroll
    for (int m = 0; m < 4; ++m)
      #pragma unroll
      for (int n = 0; n < 4; ++n)
        s[m][n] = mfma16(qf[m], kf[n], f32x4{0.f, 0.f, 0.f, 0.f});

    // bias + mask from precomputed tables (round-3 data path)
    const float* bsl = bias16 + h * 2401;
    const float* msl = mask + (size_t)wi * 2401;
    #pragma unroll
    for (int m = 0; m < 4; ++m) {
      #pragma unroll
      for (int i = 0; i < 4; ++i) {
        int rw = m * 16 + 4 * q4 + i;
        if (rw < 49) {
          const float* br = bsl + rw * 49;
          const float* mr = msl + rw * 49;
          #pragma unroll
          for (int n = 0; n < 4; ++n) {
            int j = n * 16 + c15;
            s[m][n][i] = (j < 49) ? (s[m][n][i] + br[j] + mr[j]) : -1e30f;
          }
        } else {
          #pragma unroll
          for (int n = 0; n < 4; ++n)
            if (n * 16 + c15 >= 49) s[m][n][i] = -1e30f;
        }
      }
    }

    // in-register softmax (row = 16 lanes x 4 n-tiles), libm expf as r3
    #pragma unroll
    for (int m = 0; m < 4; ++m) {
      #pragma unroll
      for (int i = 0; i < 4; ++i) {
        float mx = fmaxf(fmaxf(s[m][0][i], s[m][1][i]), fmaxf(s[m][2][i], s[m][3][i]));
        mx = fmaxf(mx, __shfl_xor(mx, 1, 64)); mx = fmaxf(mx, __shfl_xor(mx, 2, 64));
        mx = fmaxf(mx, __shfl_xor(mx, 4, 64)); mx = fmaxf(mx, __shfl_xor(mx, 8, 64));
        float sum = 0.f;
        #pragma unroll
        for (int n = 0; n < 4; ++n) { float e = expf(s[m][n][i] - mx); s[m][n][i] = e; sum += e; }
        sum += __shfl_xor(sum, 1, 64); sum += __shfl_xor(sum, 2, 64);
        sum += __shfl_xor(sum, 4, 64); sum += __shfl_xor(sum, 8, 64);
        float inv = 1.f / sum;
        #pragma unroll
        for (int n = 0; n < 4; ++n) s[m][n][i] *= inv;
      }
    }

    // write P (f32)
    #pragma unroll
    for (int m = 0; m < 4; ++m)
      #pragma unroll
      for (int n = 0; n < 4; ++n)
        #pragma unroll
        for (int i = 0; i < 4; ++i)
          Pf[h * 4352 + (m * 16 + 4 * q4 + i) * 68 + n * 16 + c15] = s[m][n][i];
    // fence: cross-lane same-wave LDS RAW — stop compiler hoisting the reads
    asm volatile("s_waitcnt lgkmcnt(0)" ::: "memory");
    __builtin_amdgcn_sched_barrier(0);

    // PV with split-precision P
    f32x4 o[4][2];
    #pragma unroll
    for (int m = 0; m < 4; ++m)
      #pragma unroll
      for (int n2 = 0; n2 < 2; ++n2) o[m][n2] = f32x4{0.f, 0.f, 0.f, 0.f};
    #pragma unroll
    for (int ks = 0; ks < 2; ++ks) {
      bf16x8 phi[4], plo[4];
      #pragma unroll
      for (int m = 0; m < 4; ++m) {
        float p8[8];
        const float* src = &Pf[h * 4352 + (m * 16 + c15) * 68 + ks * 32 + q4 * 8];
        *(float4*)&p8[0] = *(const float4*)&src[0];
        *(float4*)&p8[4] = *(const float4*)&src[4];
        split8(p8, phi[m], plo[m]);
      }
      #pragma unroll
      for (int n2 = 0; n2 < 2; ++n2) {
        bf16x8 vb = *(const bf16x8*)&VtS[h * 2304 + (n2 * 16 + c15) * 72 + ks * 32 + q4 * 8];
        #pragma unroll
        for (int m = 0; m < 4; ++m) {
          o[m][n2] = mfma16(phi[m], vb, o[m][n2]);
          o[m][n2] = mfma16(plo[m], vb, o[m][n2]);
        }
      }
    }

    // write O (bf16 pairs)
    #pragma unroll
    for (int m = 0; m < 4; ++m)
      #pragma unroll
      for (int n2 = 0; n2 < 2; ++n2)
        #pragma unroll
        for (int i = 0; i < 4; ++i) {
          float ov = o[m][n2][i];
          float on = __shfl_xor(ov, 1, 64);
          if (!(lane & 1))
            obuf[(m * 16 + 4 * q4 + i) * 52 + h * 16 + n2 * 8 + (c15 >> 1)] = packb(ov, on);
        }
  }
  __syncthreads();

  // ---- proj: wave wv handles M-tile wv ----
  bf16x8 oa[3];
  #pragma unroll
  for (int ks = 0; ks < 3; ++ks)
    oa[ks] = *(const bf16x8*)&obuf[(wv * 16 + c15) * 52 + ks * 16 + q4 * 4];
  f32x4 pr[6];
  #pragma unroll
  for (int n = 0; n < 6; ++n) pr[n] = f32x4{0.f, 0.f, 0.f, 0.f};
  #pragma unroll
  for (int n = 0; n < 6; ++n)
    #pragma unroll
    for (int ks = 0; ks < 3; ++ks) {
      bf16x8 bfr = *(const bf16x8*)&pwf[(size_t)((n * 3 + ks) * 64 + lane) * 4];
      pr[n] = mfma16(oa[ks], bfr, pr[n]);
    }

  float* ybuf = (float*)Pf;   // alias; all Pf reads done before the barrier above
  #pragma unroll
  for (int n = 0; n < 6; ++n) {
    int col = n * 16 + c15;
    float bo = proj_b[col];
    #pragma unroll
    for (int i = 0; i < 4; ++i)
      ybuf[(wv * 16 + 4 * q4 + i) * 100 + col] = pr[n][i] + bo;
  }
  __syncthreads();

  // ---- LN1 (two-pass variance, as r3) + residual scatter ----
  int t = tid >> 2, pp = tid & 3;
  if (t < 49) {
    const float* yrow = ybuf + t * 100 + pp * 24;
    float s1 = 0.f;
    #pragma unroll
    for (int c = 0; c < 24; ++c) s1 += yrow[c];
    s1 += __shfl_xor(s1, 1, 64); s1 += __shfl_xor(s1, 2, 64);
    float mu = s1 * (1.f / 96.f);
    float v2 = 0.f;
    #pragma unroll
    for (int c = 0; c < 24; ++c) { float d = yrow[c] - mu; v2 += d * d; }
    v2 += __shfl_xor(v2, 1, 64); v2 += __shfl_xor(v2, 2, 64);
    float rs = rsqrtf(v2 * (1.f / 96.f) + 1e-5f);
    size_t base = (size_t)toks[t] * 96 + pp * 24;
    #pragma unroll
    for (int c4 = 0; c4 < 6; ++c4) {
      float4 xv = *(const float4*)(x + base + c4 * 4);
      float4 gv = *(const float4*)(n1g + pp * 24 + c4 * 4);
      float4 bv = *(const float4*)(n1b + pp * 24 + c4 * 4);
      float4 ov;
      ov.x = xv.x + (yrow[c4 * 4 + 0] - mu) * rs * gv.x + bv.x;
      ov.y = xv.y + (yrow[c4 * 4 + 1] - mu) * rs * gv.y + bv.y;
      ov.z = xv.z + (yrow[c4 * 4 + 2] - mu) * rs * gv.z + bv.z;
      ov.w = xv.w + (yrow[c4 * 4 + 3] - mu) * rs * gv.w + bv.w;
      *(float4*)(out + base + c4 * 4) = ov;
    }
  }
}

// ---------------- K4: MLP via MFMA + LN2 + residual (r3, passed) --------------
__global__ __launch_bounds__(256) void mlp_mfma_kernel(
    const unsigned* __restrict__ w1f, const float* __restrict__ fc1_b,
    const unsigned* __restrict__ w2f, const float* __restrict__ fc2_b,
    const float* __restrict__ n2g, const float* __restrict__ n2b,
    float* __restrict__ xio) {
  __shared__ unsigned xa[64 * 52];
  __shared__ unsigned hid[64 * 196];
  __shared__ float mu_s[64], rs_s[64];
  int tid = threadIdx.x, lane = tid & 63, wv = tid >> 6;
  int c15 = lane & 15, q4 = lane >> 4;
  size_t tok0 = (size_t)blockIdx.x * 64;

  for (int idx = tid; idx < 3072; idx += 256) {
    int t = idx / 48, c2 = idx - t * 48;
    const float2 s = *(const float2*)(xio + (tok0 + t) * 96 + c2 * 2);
    xa[t * 52 + c2] = packb(s.x, s.y);
  }
  __syncthreads();

  bf16x8 afr[4][3];
  #pragma unroll
  for (int m = 0; m < 4; ++m)
    #pragma unroll
    for (int k = 0; k < 3; ++k)
      afr[m][k] = *(const bf16x8*)&xa[(m * 16 + c15) * 52 + k * 16 + q4 * 4];
  f32x4 acc[4][6];
  #pragma unroll
  for (int m = 0; m < 4; ++m)
    #pragma unroll
    for (int n = 0; n < 6; ++n) acc[m][n] = f32x4{0.f, 0.f, 0.f, 0.f};
  #pragma unroll
  for (int n = 0; n < 6; ++n) {
    #pragma unroll
    for (int k = 0; k < 3; ++k) {
      bf16x8 b = *(const bf16x8*)&w1f[(size_t)(((6 * wv + n) * 3 + k) * 64 + lane) * 4];
      #pragma unroll
      for (int m = 0; m < 4; ++m) acc[m][n] = mfma16(afr[m][k], b, acc[m][n]);
    }
  }
  unsigned short* hidb = (unsigned short*)hid;
  #pragma unroll
  for (int n = 0; n < 6; ++n) {
    int col = (6 * wv + n) * 16 + c15;
    float bo = fc1_b[col];
    #pragma unroll
    for (int m = 0; m < 4; ++m) {
      #pragma unroll
      for (int i = 0; i < 4; ++i) {
        float v = acc[m][n][i] + bo;
        float g = 0.5f * v * (1.f + erff(v * 0.70710678118654752f));
        hidb[(m * 16 + q4 * 4 + i) * 392 + col] = f2b(g);
      }
    }
  }
  __syncthreads();

  f32x4 acc2[6];
  #pragma unroll
  for (int n = 0; n < 6; ++n) acc2[n] = f32x4{0.f, 0.f, 0.f, 0.f};
  #pragma unroll
  for (int k = 0; k < 12; ++k) {
    bf16x8 a = *(const bf16x8*)&hid[(wv * 16 + c15) * 196 + k * 16 + q4 * 4];
    #pragma unroll
    for (int n = 0; n < 6; ++n) {
      bf16x8 b = *(const bf16x8*)&w2f[(size_t)((n * 12 + k) * 64 + lane) * 4];
      acc2[n] = mfma16(a, b, acc2[n]);
    }
  }
  __syncthreads();

  float* ybuf = (float*)hid;
  #pragma unroll
  for (int n = 0; n < 6; ++n) {
    int col = n * 16 + c15;
    float bo = fc2_b[col];
    #pragma unroll
    for (int i = 0; i < 4; ++i)
      ybuf[(wv * 16 + q4 * 4 + i) * 100 + col] = acc2[n][i] + bo;
  }
  __syncthreads();

  {
    int t = tid >> 2, p = tid & 3;
    const float* row = ybuf + t * 100 + p * 24;
    float s = 0.f, s2 = 0.f;
    for (int c = 0; c < 24; ++c) { float v = row[c]; s += v; s2 += v * v; }
    s += __shfl_xor(s, 1, 64); s2 += __shfl_xor(s2, 1, 64);
    s += __shfl_xor(s, 2, 64); s2 += __shfl_xor(s2, 2, 64);
    if (p == 0) {
      float mu = s * (1.f / 96.f);
      float var = s2 * (1.f / 96.f) - mu * mu;
      mu_s[t] = mu;
      rs_s[t] = rsqrtf(fmaxf(var, 0.f) + 1e-5f);
    }
  }
  __syncthreads();

  for (int idx = tid; idx < 6144; idx += 256) {
    int t = idx / 96, c = idx - t * 96;
    float y = ybuf[t * 100 + c];
    xio[tok0 * 96 + idx] += (y - mu_s[t]) * rs_s[t] * n2g[c] + n2b[c];
  }
}

// ---------------- launch ------------------------------------------------------
extern "C" void kernel_launch(void* const* d_in, const int* in_sizes, int n_in,
                              void* d_out, int out_size, void* d_ws, size_t ws_size,
                              hipStream_t stream) {
  const float* x           = (const float*)d_in[0];
  const float* attn_mask   = (const float*)d_in[1];
  const float* qkv_w       = (const float*)d_in[2];
  const float* q_bias      = (const float*)d_in[3];
  const float* v_bias      = (const float*)d_in[4];
  const float* logit_scale = (const float*)d_in[5];
  const float* cpb_w1      = (const float*)d_in[6];
  const float* cpb_b1      = (const float*)d_in[7];
  const float* cpb_w2      = (const float*)d_in[8];
  const float* proj_w      = (const float*)d_in[9];
  const float* proj_b      = (const float*)d_in[10];
  const float* n1g         = (const float*)d_in[11];
  const float* n1b         = (const float*)d_in[12];
  const float* fc1_w       = (const float*)d_in[13];
  const float* fc1_b       = (const float*)d_in[14];
  const float* fc2_w       = (const float*)d_in[15];
  const float* fc2_b       = (const float*)d_in[16];
  const float* n2g         = (const float*)d_in[17];
  const float* n2b         = (const float*)d_in[18];
  float* out = (float*)d_out;

  // ---- workspace layout ----
  float* tab     = (float*)d_ws;                       // 512 f32
  float* bias16  = tab + 512;                          // 7296 f32
  unsigned* qkvf = (unsigned*)(bias16 + 7296);         // 13824 dw
  unsigned* w1f  = qkvf + 13824;                       // 18432 dw
  unsigned* w2f  = w1f + 18432;                        // 18432 dw
  unsigned* pwf  = w2f + 18432;                        // 4608 dw
  unsigned* qws  = pwf + 4608;                         // 9,633,792 dw each
  unsigned* kws  = qws + 9633792;
  unsigned* vws  = kws + 9633792;

  wconv2_kernel<<<54, 256, 0, stream>>>(qkv_w, fc1_w, fc2_w, proj_w,
                                        qkvf, w1f, w2f, pwf);
  cpb_table_kernel<<<1, 512, 0, stream>>>(cpb_w1, cpb_b1, cpb_w2, tab);
  bias_kernel<<<(NHEADS * NTOK * NTOK + 255) / 256, 256, 0, stream>>>(tab, bias16);
  qkv_mfma_kernel<<<NTOKENS / 64, 256, 0, stream>>>(x, qkvf, q_bias, v_bias,
                                                    logit_scale, qws, kws, vws);
  attn_fused_kernel<<<NWIN_TOT, 256, 0, stream>>>(qws, kws, vws, bias16, attn_mask,
                                                  pwf, proj_b, x, n1g, n1b, out);
  mlp_mfma_kernel<<<NTOKENS / 64, 256, 0, stream>>>(w1f, fc1_b, w2f, fc2_b,
                                                    n2g, n2b, out);
}

// Round 7
// 495.942 us; speedup vs baseline: 10.0839x; 1.0724x over previous
//
#include <hip/hip_runtime.h>
#include <math.h>

#define BATCH 64
#define HW 56
#define CDIM 96
#define NHEADS 3
#define WSZ 7
#define NTOK 49
#define SHIFT_ 3
#define NWIN_TOT 4096
#define HID 384
#define NTOKENS (BATCH * HW * HW)   // 200704
#define LN100 4.6051702f

typedef __attribute__((ext_vector_type(8))) short bf16x8;
typedef __attribute__((ext_vector_type(4))) float f32x4;

__device__ inline f32x4 mfma16(bf16x8 a, bf16x8 b, f32x4 c) {
  return __builtin_amdgcn_mfma_f32_16x16x32_bf16(a, b, c, 0, 0, 0);
}

// ---------- bf16 helpers ----------
__device__ inline unsigned short f2b(float f) {
  unsigned u = __float_as_uint(f);
  unsigned r = (u + 0x7FFFu + ((u >> 16) & 1u)) >> 16;
  return (unsigned short)r;
}
__device__ inline float blo(unsigned u) { return __uint_as_float(u << 16); }
__device__ inline unsigned packb(float a, float b) {
  return (unsigned)f2b(a) | ((unsigned)f2b(b) << 16);
}
// split f32 -> (hi, lo) bf16 fragments: hi+lo reproduces p to ~2^-18
__device__ inline void split8(const float* p, bf16x8& hi, bf16x8& lo) {
  short h8[8], l8[8];
  #pragma unroll
  for (int j = 0; j < 8; ++j) {
    unsigned short h = f2b(p[j]);
    float hf = __uint_as_float((unsigned)h << 16);
    h8[j] = (short)h;
    l8[j] = (short)f2b(p[j] - hf);
  }
  hi = bf16x8{h8[0], h8[1], h8[2], h8[3], h8[4], h8[5], h8[6], h8[7]};
  lo = bf16x8{l8[0], l8[1], l8[2], l8[3], l8[4], l8[5], l8[6], l8[7]};
}
// GELU with A&S 7.1.26 erf (max abs err 1.5e-7) — 4 orders below bf16 noise
__device__ inline float gelu_f(float v) {
  float a = fabsf(v) * 0.70710678118654752f;
  float t = 1.0f / fmaf(a, 0.3275911f, 1.0f);
  float p = t * fmaf(t, fmaf(t, fmaf(t, fmaf(t, 1.061405429f, -1.453152027f),
                                     1.421413741f), -0.284496736f), 0.254829592f);
  float er = 1.0f - p * __expf(-a * a);
  er = (v < 0.f) ? -er : er;
  return 0.5f * v * (1.0f + er);
}

// ---------------- P0: weight conversion into MFMA B-frag layouts --------------
__global__ __launch_bounds__(256) void wconv2_kernel(
    const float* __restrict__ qkv_w, const float* __restrict__ fc1_w,
    const float* __restrict__ fc2_w, const float* __restrict__ proj_w,
    unsigned* __restrict__ qkvf, unsigned* __restrict__ w1f,
    unsigned* __restrict__ w2f, unsigned* __restrict__ pwf) {
  int T = blockIdx.x * 256 + threadIdx.x;
  if (T < 3456) {  // qkv: 18 n-tiles x 3 k-steps
    int tk = T >> 6, l = T & 63;
    int n = tk / 3, ks = tk - n * 3;
    int o = n * 16 + (l & 15);
    const float* src = qkv_w + o * 96 + ks * 32 + (l >> 4) * 8;
    uint4 d;
    d.x = packb(src[0], src[1]); d.y = packb(src[2], src[3]);
    d.z = packb(src[4], src[5]); d.w = packb(src[6], src[7]);
    *(uint4*)&qkvf[(size_t)(tk * 64 + l) * 4] = d;
    return;
  }
  T -= 3456;
  if (T < 4608) {  // fc1
    int tk = T >> 6, l = T & 63;
    int n = tk / 3, ks = tk - n * 3;
    int o = n * 16 + (l & 15);
    const float* src = fc1_w + o * 96 + ks * 32 + (l >> 4) * 8;
    uint4 d;
    d.x = packb(src[0], src[1]); d.y = packb(src[2], src[3]);
    d.z = packb(src[4], src[5]); d.w = packb(src[6], src[7]);
    *(uint4*)&w1f[(size_t)(tk * 64 + l) * 4] = d;
    return;
  }
  T -= 4608;
  if (T < 4608) {  // fc2
    int tk = T >> 6, l = T & 63;
    int n = tk / 12, ks = tk - n * 12;
    int o = n * 16 + (l & 15);
    const float* src = fc2_w + o * 384 + ks * 32 + (l >> 4) * 8;
    uint4 d;
    d.x = packb(src[0], src[1]); d.y = packb(src[2], src[3]);
    d.z = packb(src[4], src[5]); d.w = packb(src[6], src[7]);
    *(uint4*)&w2f[(size_t)(tk * 64 + l) * 4] = d;
    return;
  }
  T -= 4608;
  if (T < 1152) {  // proj
    int tk = T >> 6, l = T & 63;
    int n = tk / 3, ks = tk - n * 3;
    int o = n * 16 + (l & 15);
    const float* src = proj_w + o * 96 + ks * 32 + (l >> 4) * 8;
    uint4 d;
    d.x = packb(src[0], src[1]); d.y = packb(src[2], src[3]);
    d.z = packb(src[4], src[5]); d.w = packb(src[6], src[7]);
    *(uint4*)&pwf[(size_t)(tk * 64 + l) * 4] = d;
  }
}

// ---------------- P1: CPB MLP table raw (169 x 3) -----------------------------
__global__ __launch_bounds__(512) void cpb_table_kernel(
    const float* __restrict__ w1, const float* __restrict__ b1,
    const float* __restrict__ w2, float* __restrict__ tabout) {
  int tid = threadIdx.x;
  if (tid >= 169 * 3) return;
  int e = tid / 3, h = tid - e * 3;
  int i = e / 13, j = e - i * 13;
  float ti = (float)(i - 6) * (8.0f / 6.0f);
  float tj = (float)(j - 6) * (8.0f / 6.0f);
  float sx = (ti > 0.f) ? 1.f : (ti < 0.f ? -1.f : 0.f);
  float sy = (tj > 0.f) ? 1.f : (tj < 0.f ? -1.f : 0.f);
  float tx = sx * log2f(fabsf(ti) + 1.f) * (1.0f / 3.0f);
  float ty = sy * log2f(fabsf(tj) + 1.f) * (1.0f / 3.0f);
  float acc = 0.f;
  for (int jj = 0; jj < 512; ++jj) {
    float hv = tx * w1[jj * 2 + 0] + ty * w1[jj * 2 + 1] + b1[jj];
    float g = 0.5f * hv * (1.f + erff(hv * 0.70710678118654752f));
    acc += g * w2[h * 512 + jj];
  }
  tabout[e * 3 + h] = acc;
}

// ---------------- P2: 16*sigmoid(rpb) gathered to (3,49,49) -------------------
__global__ __launch_bounds__(256) void bias_kernel(
    const float* __restrict__ tabout, float* __restrict__ bias16) {
  int idx = blockIdx.x * 256 + threadIdx.x;
  if (idx >= NHEADS * NTOK * NTOK) return;
  int h = idx / (NTOK * NTOK);
  int rem = idx - h * NTOK * NTOK;
  int i = rem / NTOK, j = rem - i * NTOK;
  int ri = (i / WSZ) - (j / WSZ) + 6;
  int ci = (i % WSZ) - (j % WSZ) + 6;
  int e = ri * 13 + ci;
  float v = tabout[e * 3 + h];
  bias16[idx] = 16.f / (1.f + expf(-v));
}

// ---------------- K1: token-major QKV GEMM (MFMA) + cosine norm ---------------
__global__ __launch_bounds__(256) void qkv_mfma_kernel(
    const float* __restrict__ x, const unsigned* __restrict__ qkvf,
    const float* __restrict__ q_bias, const float* __restrict__ v_bias,
    const float* __restrict__ logit_scale,
    unsigned* __restrict__ qws, unsigned* __restrict__ kws,
    unsigned* __restrict__ vws) {
  __shared__ unsigned xa[64 * 52];
  int tid = threadIdx.x, lane = tid & 63, wv = tid >> 6;
  size_t tok0 = (size_t)blockIdx.x * 64;

  for (int idx = tid; idx < 3072; idx += 256) {
    int t = idx / 48, c2 = idx - t * 48;
    const float2 s = *(const float2*)(x + (tok0 + t) * 96 + c2 * 2);
    xa[t * 52 + c2] = packb(s.x, s.y);
  }
  __syncthreads();

  int c15 = lane & 15, q4 = lane >> 4;
  bf16x8 afr[3];
  #pragma unroll
  for (int k = 0; k < 3; ++k)
    afr[k] = *(const bf16x8*)&xa[(wv * 16 + c15) * 52 + k * 16 + q4 * 4];

  f32x4 acc[18];
  #pragma unroll
  for (int n = 0; n < 18; ++n) acc[n] = f32x4{0.f, 0.f, 0.f, 0.f};
  #pragma unroll
  for (int n = 0; n < 18; ++n) {
    #pragma unroll
    for (int k = 0; k < 3; ++k) {
      bf16x8 b = *(const bf16x8*)&qkvf[(size_t)((n * 3 + k) * 64 + lane) * 4];
      acc[n] = mfma16(afr[k], b, acc[n]);
    }
  }

  int tokr0 = (int)tok0 + wv * 16 + q4 * 4;
  #pragma unroll
  for (int h = 0; h < 3; ++h) {
    float sc = expf(fminf(logit_scale[h], LN100));
    {   // q
      f32x4 a0 = acc[2 * h], a1 = acc[2 * h + 1];
      float b0 = q_bias[h * 32 + c15], b1 = q_bias[h * 32 + 16 + c15];
      unsigned pk[8];
      #pragma unroll
      for (int i = 0; i < 4; ++i) {
        float va = a0[i] + b0, vb = a1[i] + b1;
        float ss = va * va + vb * vb;
        ss += __shfl_xor(ss, 1, 64); ss += __shfl_xor(ss, 2, 64);
        ss += __shfl_xor(ss, 4, 64); ss += __shfl_xor(ss, 8, 64);
        float inv = sc / fmaxf(sqrtf(ss), 1e-12f);
        va *= inv; vb *= inv;
        float pa = __shfl_xor(va, 1, 64), pb = __shfl_xor(vb, 1, 64);
        pk[i] = packb(va, pa); pk[4 + i] = packb(vb, pb);
      }
      if (!(lane & 1)) {
        int dw0 = c15 >> 1;
        #pragma unroll
        for (int i = 0; i < 4; ++i) {
          size_t base = ((size_t)(tokr0 + i) * 3 + h) * 16;
          qws[base + dw0] = pk[i];
          qws[base + 8 + dw0] = pk[4 + i];
        }
      }
    }
    {   // k
      f32x4 a0 = acc[6 + 2 * h], a1 = acc[7 + 2 * h];
      unsigned pk[8];
      #pragma unroll
      for (int i = 0; i < 4; ++i) {
        float va = a0[i], vb = a1[i];
        float ss = va * va + vb * vb;
        ss += __shfl_xor(ss, 1, 64); ss += __shfl_xor(ss, 2, 64);
        ss += __shfl_xor(ss, 4, 64); ss += __shfl_xor(ss, 8, 64);
        float inv = 1.f / fmaxf(sqrtf(ss), 1e-12f);
        va *= inv; vb *= inv;
        float pa = __shfl_xor(va, 1, 64), pb = __shfl_xor(vb, 1, 64);
        pk[i] = packb(va, pa); pk[4 + i] = packb(vb, pb);
      }
      if (!(lane & 1)) {
        int dw0 = c15 >> 1;
        #pragma unroll
        for (int i = 0; i < 4; ++i) {
          size_t base = ((size_t)(tokr0 + i) * 3 + h) * 16;
          kws[base + dw0] = pk[i];
          kws[base + 8 + dw0] = pk[4 + i];
        }
      }
    }
    {   // v
      f32x4 a0 = acc[12 + 2 * h], a1 = acc[13 + 2 * h];
      float b0 = v_bias[h * 32 + c15], b1 = v_bias[h * 32 + 16 + c15];
      unsigned pk[8];
      #pragma unroll
      for (int i = 0; i < 4; ++i) {
        float va = a0[i] + b0, vb = a1[i] + b1;
        float pa = __shfl_xor(va, 1, 64), pb = __shfl_xor(vb, 1, 64);
        pk[i] = packb(va, pa); pk[4 + i] = packb(vb, pb);
      }
      if (!(lane & 1)) {
        int dw0 = c15 >> 1;
        #pragma unroll
        for (int i = 0; i < 4; ++i) {
          size_t base = ((size_t)(tokr0 + i) * 3 + h) * 16;
          vws[base + dw0] = pk[i];
          vws[base + 8 + dw0] = pk[4 + i];
        }
      }
    }
  }
}

// ---------------- K2: fused attention + proj + LN1 ----------------------------
__global__ __launch_bounds__(256) void attn_fused_kernel(
    const unsigned* __restrict__ qws, const unsigned* __restrict__ kws,
    const unsigned* __restrict__ vws, const float* __restrict__ bias16,
    const float* __restrict__ mask, const unsigned* __restrict__ pwf,
    const float* __restrict__ proj_b, const float* __restrict__ x,
    const float* __restrict__ n1g, const float* __restrict__ n1b,
    float* __restrict__ out) {
  __shared__ int toks[64];                     //   256 B
  __shared__ unsigned short VtS[3 * 32 * 72];  // 13824 B (cols 49..63 = clamped junk, P=0 there)
  __shared__ float Pf[3 * 64 * 68];            // 52224 B; later ybuf f32[64][100]
  __shared__ unsigned obuf[64 * 52];           // 13312 B

  int tid = threadIdx.x, lane = tid & 63, wv = tid >> 6;
  int c15 = lane & 15, q4 = lane >> 4;
  int win = blockIdx.x;
  int b = win >> 6, wi = win & 63, wh = wi >> 3, wcx = wi & 7;

  if (tid < 64) {
    int t = tid < 49 ? tid : 48;
    int tr = (t * 9363) >> 16, tc = t - tr * 7;
    int R = wh * 7 + tr + SHIFT_; if (R >= HW) R -= HW;
    int C = wcx * 7 + tc + SHIFT_; if (C >= HW) C -= HW;
    toks[tid] = b * 3136 + R * 56 + C;
  }
  __syncthreads();

  // hoist q/k fragment gathers so their latency overlaps V staging
  bf16x8 qf[4], kf[4];
  if (wv < 3) {
    #pragma unroll
    for (int m = 0; m < 4; ++m)
      qf[m] = *(const bf16x8*)&qws[((size_t)toks[m * 16 + c15] * 3 + wv) * 16 + q4 * 4];
    #pragma unroll
    for (int n = 0; n < 4; ++n)
      kf[n] = *(const bf16x8*)&kws[((size_t)toks[n * 16 + c15] * 3 + wv) * 16 + q4 * 4];
  }

  // stage V transposed: all 64 column slots (clamped), uint4 gathers
  for (int idx = tid; idx < 768; idx += 256) {
    int h2 = idx >> 8, rem = idx & 255;
    int t = rem >> 2, dg = rem & 3;
    uint4 v4 = *(const uint4*)&vws[((size_t)toks[t] * 3 + h2) * 16 + dg * 4];
    unsigned short* dst = &VtS[h2 * 2304 + (dg * 8) * 72 + t];
    dst[0 * 72] = (unsigned short)(v4.x & 0xFFFFu); dst[1 * 72] = (unsigned short)(v4.x >> 16);
    dst[2 * 72] = (unsigned short)(v4.y & 0xFFFFu); dst[3 * 72] = (unsigned short)(v4.y >> 16);
    dst[4 * 72] = (unsigned short)(v4.z & 0xFFFFu); dst[5 * 72] = (unsigned short)(v4.z >> 16);
    dst[6 * 72] = (unsigned short)(v4.w & 0xFFFFu); dst[7 * 72] = (unsigned short)(v4.w >> 16);
  }
  __syncthreads();

  if (wv < 3) {
    int h = wv;
    f32x4 s[4][4];
    #pragma unroll
    for (int m = 0; m < 4; ++m)
      #pragma unroll
      for (int n = 0; n < 4; ++n)
        s[m][n] = mfma16(qf[m], kf[n], f32x4{0.f, 0.f, 0.f, 0.f});

    // bias + mask from precomputed tables
    const float* bsl = bias16 + h * 2401;
    const float* msl = mask + (size_t)wi * 2401;
    #pragma unroll
    for (int m = 0; m < 4; ++m) {
      #pragma unroll
      for (int i = 0; i < 4; ++i) {
        int rw = m * 16 + 4 * q4 + i;
        if (rw < 49) {
          const float* br = bsl + rw * 49;
          const float* mr = msl + rw * 49;
          #pragma unroll
          for (int n = 0; n < 4; ++n) {
            int j = n * 16 + c15;
            s[m][n][i] = (j < 49) ? (s[m][n][i] + br[j] + mr[j]) : -1e30f;
          }
        } else {
          #pragma unroll
          for (int n = 0; n < 4; ++n)
            if (n * 16 + c15 >= 49) s[m][n][i] = -1e30f;
        }
      }
    }

    // in-register softmax; __expf = v_exp_f32 (<=2 ulp)
    #pragma unroll
    for (int m = 0; m < 4; ++m) {
      #pragma unroll
      for (int i = 0; i < 4; ++i) {
        float mx = fmaxf(fmaxf(s[m][0][i], s[m][1][i]), fmaxf(s[m][2][i], s[m][3][i]));
        mx = fmaxf(mx, __shfl_xor(mx, 1, 64)); mx = fmaxf(mx, __shfl_xor(mx, 2, 64));
        mx = fmaxf(mx, __shfl_xor(mx, 4, 64)); mx = fmaxf(mx, __shfl_xor(mx, 8, 64));
        float sum = 0.f;
        #pragma unroll
        for (int n = 0; n < 4; ++n) { float e = __expf(s[m][n][i] - mx); s[m][n][i] = e; sum += e; }
        sum += __shfl_xor(sum, 1, 64); sum += __shfl_xor(sum, 2, 64);
        sum += __shfl_xor(sum, 4, 64); sum += __shfl_xor(sum, 8, 64);
        float inv = 1.f / sum;
        #pragma unroll
        for (int n = 0; n < 4; ++n) s[m][n][i] *= inv;
      }
    }

    // write P (f32)
    #pragma unroll
    for (int m = 0; m < 4; ++m)
      #pragma unroll
      for (int n = 0; n < 4; ++n)
        #pragma unroll
        for (int i = 0; i < 4; ++i)
          Pf[h * 4352 + (m * 16 + 4 * q4 + i) * 68 + n * 16 + c15] = s[m][n][i];
    // fence: cross-lane same-wave LDS RAW
    asm volatile("s_waitcnt lgkmcnt(0)" ::: "memory");
    __builtin_amdgcn_sched_barrier(0);

    // PV with split-precision P
    f32x4 o[4][2];
    #pragma unroll
    for (int m = 0; m < 4; ++m)
      #pragma unroll
      for (int n2 = 0; n2 < 2; ++n2) o[m][n2] = f32x4{0.f, 0.f, 0.f, 0.f};
    #pragma unroll
    for (int ks = 0; ks < 2; ++ks) {
      bf16x8 phi[4], plo[4];
      #pragma unroll
      for (int m = 0; m < 4; ++m) {
        float p8[8];
        const float* src = &Pf[h * 4352 + (m * 16 + c15) * 68 + ks * 32 + q4 * 8];
        *(float4*)&p8[0] = *(const float4*)&src[0];
        *(float4*)&p8[4] = *(const float4*)&src[4];
        split8(p8, phi[m], plo[m]);
      }
      #pragma unroll
      for (int n2 = 0; n2 < 2; ++n2) {
        bf16x8 vb = *(const bf16x8*)&VtS[h * 2304 + (n2 * 16 + c15) * 72 + ks * 32 + q4 * 8];
        #pragma unroll
        for (int m = 0; m < 4; ++m) {
          o[m][n2] = mfma16(phi[m], vb, o[m][n2]);
          o[m][n2] = mfma16(plo[m], vb, o[m][n2]);
        }
      }
    }

    // write O (bf16 pairs)
    #pragma unroll
    for (int m = 0; m < 4; ++m)
      #pragma unroll
      for (int n2 = 0; n2 < 2; ++n2)
        #pragma unroll
        for (int i = 0; i < 4; ++i) {
          float ov = o[m][n2][i];
          float on = __shfl_xor(ov, 1, 64);
          if (!(lane & 1))
            obuf[(m * 16 + 4 * q4 + i) * 52 + h * 16 + n2 * 8 + (c15 >> 1)] = packb(ov, on);
        }
  }
  __syncthreads();

  // ---- proj: wave wv handles M-tile wv ----
  bf16x8 oa[3];
  #pragma unroll
  for (int ks = 0; ks < 3; ++ks)
    oa[ks] = *(const bf16x8*)&obuf[(wv * 16 + c15) * 52 + ks * 16 + q4 * 4];
  f32x4 pr[6];
  #pragma unroll
  for (int n = 0; n < 6; ++n) pr[n] = f32x4{0.f, 0.f, 0.f, 0.f};
  #pragma unroll
  for (int n = 0; n < 6; ++n)
    #pragma unroll
    for (int ks = 0; ks < 3; ++ks) {
      bf16x8 bfr = *(const bf16x8*)&pwf[(size_t)((n * 3 + ks) * 64 + lane) * 4];
      pr[n] = mfma16(oa[ks], bfr, pr[n]);
    }

  float* ybuf = (float*)Pf;   // alias; all Pf reads done before the barrier above
  #pragma unroll
  for (int n = 0; n < 6; ++n) {
    int col = n * 16 + c15;
    float bo = proj_b[col];
    #pragma unroll
    for (int i = 0; i < 4; ++i)
      ybuf[(wv * 16 + 4 * q4 + i) * 100 + col] = pr[n][i] + bo;
  }
  __syncthreads();

  // ---- LN1 (two-pass variance) + residual scatter ----
  int t = tid >> 2, pp = tid & 3;
  if (t < 49) {
    const float* yrow = ybuf + t * 100 + pp * 24;
    float s1 = 0.f;
    #pragma unroll
    for (int c = 0; c < 24; ++c) s1 += yrow[c];
    s1 += __shfl_xor(s1, 1, 64); s1 += __shfl_xor(s1, 2, 64);
    float mu = s1 * (1.f / 96.f);
    float v2 = 0.f;
    #pragma unroll
    for (int c = 0; c < 24; ++c) { float d = yrow[c] - mu; v2 += d * d; }
    v2 += __shfl_xor(v2, 1, 64); v2 += __shfl_xor(v2, 2, 64);
    float rs = rsqrtf(v2 * (1.f / 96.f) + 1e-5f);
    size_t base = (size_t)toks[t] * 96 + pp * 24;
    #pragma unroll
    for (int c4 = 0; c4 < 6; ++c4) {
      float4 xv = *(const float4*)(x + base + c4 * 4);
      float4 gv = *(const float4*)(n1g + pp * 24 + c4 * 4);
      float4 bv = *(const float4*)(n1b + pp * 24 + c4 * 4);
      float4 ov;
      ov.x = xv.x + (yrow[c4 * 4 + 0] - mu) * rs * gv.x + bv.x;
      ov.y = xv.y + (yrow[c4 * 4 + 1] - mu) * rs * gv.y + bv.y;
      ov.z = xv.z + (yrow[c4 * 4 + 2] - mu) * rs * gv.z + bv.z;
      ov.w = xv.w + (yrow[c4 * 4 + 3] - mu) * rs * gv.w + bv.w;
      *(float4*)(out + base + c4 * 4) = ov;
    }
  }
}

// ---------------- K4: MLP via MFMA + LN2 + residual (in-place) ----------------
__global__ __launch_bounds__(256) void mlp_mfma_kernel(
    const unsigned* __restrict__ w1f, const float* __restrict__ fc1_b,
    const unsigned* __restrict__ w2f, const float* __restrict__ fc2_b,
    const float* __restrict__ n2g, const float* __restrict__ n2b,
    float* __restrict__ xio) {
  __shared__ unsigned xa[64 * 52];
  __shared__ unsigned hid[64 * 196];
  __shared__ float mu_s[64], rs_s[64];
  int tid = threadIdx.x, lane = tid & 63, wv = tid >> 6;
  int c15 = lane & 15, q4 = lane >> 4;
  size_t tok0 = (size_t)blockIdx.x * 64;

  for (int idx = tid; idx < 3072; idx += 256) {
    int t = idx / 48, c2 = idx - t * 48;
    const float2 s = *(const float2*)(xio + (tok0 + t) * 96 + c2 * 2);
    xa[t * 52 + c2] = packb(s.x, s.y);
  }
  __syncthreads();

  bf16x8 afr[4][3];
  #pragma unroll
  for (int m = 0; m < 4; ++m)
    #pragma unroll
    for (int k = 0; k < 3; ++k)
      afr[m][k] = *(const bf16x8*)&xa[(m * 16 + c15) * 52 + k * 16 + q4 * 4];
  f32x4 acc[4][6];
  #pragma unroll
  for (int m = 0; m < 4; ++m)
    #pragma unroll
    for (int n = 0; n < 6; ++n) acc[m][n] = f32x4{0.f, 0.f, 0.f, 0.f};
  #pragma unroll
  for (int n = 0; n < 6; ++n) {
    #pragma unroll
    for (int k = 0; k < 3; ++k) {
      bf16x8 b = *(const bf16x8*)&w1f[(size_t)(((6 * wv + n) * 3 + k) * 64 + lane) * 4];
      #pragma unroll
      for (int m = 0; m < 4; ++m) acc[m][n] = mfma16(afr[m][k], b, acc[m][n]);
    }
  }
  unsigned short* hidb = (unsigned short*)hid;
  #pragma unroll
  for (int n = 0; n < 6; ++n) {
    int col = (6 * wv + n) * 16 + c15;
    float bo = fc1_b[col];
    #pragma unroll
    for (int m = 0; m < 4; ++m) {
      #pragma unroll
      for (int i = 0; i < 4; ++i) {
        float g = gelu_f(acc[m][n][i] + bo);
        hidb[(m * 16 + q4 * 4 + i) * 392 + col] = f2b(g);
      }
    }
  }
  __syncthreads();

  f32x4 acc2[6];
  #pragma unroll
  for (int n = 0; n < 6; ++n) acc2[n] = f32x4{0.f, 0.f, 0.f, 0.f};
  #pragma unroll
  for (int k = 0; k < 12; ++k) {
    bf16x8 a = *(const bf16x8*)&hid[(wv * 16 + c15) * 196 + k * 16 + q4 * 4];
    #pragma unroll
    for (int n = 0; n < 6; ++n) {
      bf16x8 b = *(const bf16x8*)&w2f[(size_t)((n * 12 + k) * 64 + lane) * 4];
      acc2[n] = mfma16(a, b, acc2[n]);
    }
  }
  __syncthreads();

  float* ybuf = (float*)hid;
  #pragma unroll
  for (int n = 0; n < 6; ++n) {
    int col = n * 16 + c15;
    float bo = fc2_b[col];
    #pragma unroll
    for (int i = 0; i < 4; ++i)
      ybuf[(wv * 16 + q4 * 4 + i) * 100 + col] = acc2[n][i] + bo;
  }
  __syncthreads();

  {
    int t = tid >> 2, p = tid & 3;
    const float* row = ybuf + t * 100 + p * 24;
    float s = 0.f, s2 = 0.f;
    for (int c = 0; c < 24; ++c) { float v = row[c]; s += v; s2 += v * v; }
    s += __shfl_xor(s, 1, 64); s2 += __shfl_xor(s2, 1, 64);
    s += __shfl_xor(s, 2, 64); s2 += __shfl_xor(s2, 2, 64);
    if (p == 0) {
      float mu = s * (1.f / 96.f);
      float var = s2 * (1.f / 96.f) - mu * mu;
      mu_s[t] = mu;
      rs_s[t] = rsqrtf(fmaxf(var, 0.f) + 1e-5f);
    }
  }
  __syncthreads();

  for (int idx = tid; idx < 6144; idx += 256) {
    int t = idx / 96, c = idx - t * 96;
    float y = ybuf[t * 100 + c];
    xio[tok0 * 96 + idx] += (y - mu_s[t]) * rs_s[t] * n2g[c] + n2b[c];
  }
}

// ---------------- launch ------------------------------------------------------
extern "C" void kernel_launch(void* const* d_in, const int* in_sizes, int n_in,
                              void* d_out, int out_size, void* d_ws, size_t ws_size,
                              hipStream_t stream) {
  const float* x           = (const float*)d_in[0];
  const float* attn_mask   = (const float*)d_in[1];
  const float* qkv_w       = (const float*)d_in[2];
  const float* q_bias      = (const float*)d_in[3];
  const float* v_bias      = (const float*)d_in[4];
  const float* logit_scale = (const float*)d_in[5];
  const float* cpb_w1      = (const float*)d_in[6];
  const float* cpb_b1      = (const float*)d_in[7];
  const float* cpb_w2      = (const float*)d_in[8];
  const float* proj_w      = (const float*)d_in[9];
  const float* proj_b      = (const float*)d_in[10];
  const float* n1g         = (const float*)d_in[11];
  const float* n1b         = (const float*)d_in[12];
  const float* fc1_w       = (const float*)d_in[13];
  const float* fc1_b       = (const float*)d_in[14];
  const float* fc2_w       = (const float*)d_in[15];
  const float* fc2_b       = (const float*)d_in[16];
  const float* n2g         = (const float*)d_in[17];
  const float* n2b         = (const float*)d_in[18];
  float* out = (float*)d_out;

  // ---- workspace layout ----
  float* tab     = (float*)d_ws;                       // 512 f32
  float* bias16  = tab + 512;                          // 7296 f32
  unsigned* qkvf = (unsigned*)(bias16 + 7296);         // 13824 dw
  unsigned* w1f  = qkvf + 13824;                       // 18432 dw
  unsigned* w2f  = w1f + 18432;                        // 18432 dw
  unsigned* pwf  = w2f + 18432;                        // 4608 dw
  unsigned* qws  = pwf + 4608;                         // 9,633,792 dw each
  unsigned* kws  = qws + 9633792;
  unsigned* vws  = kws + 9633792;

  wconv2_kernel<<<54, 256, 0, stream>>>(qkv_w, fc1_w, fc2_w, proj_w,
                                        qkvf, w1f, w2f, pwf);
  cpb_table_kernel<<<1, 512, 0, stream>>>(cpb_w1, cpb_b1, cpb_w2, tab);
  bias_kernel<<<(NHEADS * NTOK * NTOK + 255) / 256, 256, 0, stream>>>(tab, bias16);
  qkv_mfma_kernel<<<NTOKENS / 64, 256, 0, stream>>>(x, qkvf, q_bias, v_bias,
                                                    logit_scale, qws, kws, vws);
  attn_fused_kernel<<<NWIN_TOT, 256, 0, stream>>>(qws, kws, vws, bias16, attn_mask,
                                                  pwf, proj_b, x, n1g, n1b, out);
  mlp_mfma_kernel<<<NTOKENS / 64, 256, 0, stream>>>(w1f, fc1_b, w2f, fc2_b,
                                                    n2g, n2b, out);
}